// Round 15
// baseline (952.244 us; speedup 1.0000x reference)
//
#include <hip/hip_runtime.h>

#define DEV __device__ __forceinline__

constexpr int N = 50000;
constexpr int E = 800000;
constexpr int NBUK = 196;

// ---- float region (4-byte units) ----
constexpr int HF_OFF  = 0;
constexpr int H0F_OFF = 64*N;
constexpr int MTF_OFF = 128*N;              // bf16 hsT (aliased PBT)
constexpr int MFF_OFF = 160*N;              // bf16 hsF (aliased PBF)
constexpr int PBT_OFF = MTF_OFF;
constexpr int PBF_OFF = MFF_OFF;
constexpr int R1_OFF  = 192*N;
constexpr int PAT_OFF = R1_OFF;
constexpr int PAF_OFF = R1_OFF + 64*N;
constexpr int AL_OFF  = R1_OFF;
constexpr int RH_OFF  = R1_OFF + 64*N;
constexpr int T1_OFF  = R1_OFF;
constexpr int EV_OFF  = R1_OFF + 64*N;
constexpr int CSTG_OFF = R1_OFF;
constexpr int RSTG_OFF = R1_OFF + 4*E;
constexpr int HB_OFF   = 352*N;
constexpr int UV_OFF   = 384*N;
constexpr int LOSS_OFF = UV_OFF + N;
constexpr int FLAG_OFF = LOSS_OFF + 7;
constexpr int WZR_OFF = LOSS_OFF + 8;
constexpr int GB_OFF  = WZR_OFF + 24832;
constexpr int CW_OFF  = GB_OFF + 128;
constexpr int CB_OFF  = CW_OFF + 12416;
constexpr int PT1_OFF = CB_OFF + 64;
constexpr int AT_OFF  = PT1_OFF + 8192;
constexpr int BT1_OFF = AT_OFF + 192;
constexpr int WT2_OFF = BT1_OFF + 64;
constexpr int BT2_OFF = WT2_OFF + 4096;
constexpr int PF1_OFF = BT2_OFF + 64;
constexpr int AF_OFF  = PF1_OFF + 8192;
constexpr int BF1_OFF = AF_OFF + 192;
constexpr int WF2_OFF = BF1_OFF + 64;
constexpr int BF2_OFF = WF2_OFF + 4096;
constexpr int DW1_OFF = BF2_OFF + 64;
constexpr int DW2_OFF = DW1_OFF + 4096;
constexpr int DB1_OFF = DW2_OFF + 64;
constexpr int DB2_OFF = DB1_OFF + 64;
constexpr int EW1_OFF = DB2_OFF + 4;
constexpr int EB1_OFF = EW1_OFF + 64;
constexpr int EW2_OFF = EB1_OFF + 64;
constexpr int EB2_OFF = EW2_OFF + 4096;
constexpr int PRB0_OFF = EB2_OFF + 64;
constexpr int PRB1_OFF = PRB0_OFF + N;
constexpr int NWZR_OFF = PRB1_OFF + N;      // 196*128
constexpr int NCW_OFF  = NWZR_OFF + 25088;  // 196*64
constexpr int CNT_OFF  = NCW_OFF + 12544;   // 2N
constexpr int FEND     = CNT_OFF + 2*N;
constexpr int CREC_OFF = FEND;
constexpr int RREC_OFF = CREC_OFF + 2*E;
constexpr int LCP_OFF  = RREC_OFF + 4*E;
constexpr int FRP_OFF  = LCP_OFF + N + 1;
constexpr int LE_OFF   = FRP_OFF + N + 1;
constexpr int LCF_OFF  = LE_OFF + N;
constexpr int LRF_OFF  = LCF_OFF + N;
constexpr int SFF_OFF  = LRF_OFF + N;
constexpr int CDEG_OFF = SFF_OFF + N;
constexpr int RDEG_OFF = CDEG_OFF + N;
constexpr int SDEG_OFF = RDEG_OFF + N;
constexpr int BS_OFF   = SDEG_OFF + N;
constexpr int BO_OFF   = BS_OFF + 512;
constexpr int GFC_OFF  = BO_OFF + 512;
constexpr int GFR_OFF  = GFC_OFF + 196;
constexpr int BKC_OFF  = GFR_OFF + 196;
constexpr int BKR_OFF  = BKC_OFF + 196;
constexpr int GBC_OFF  = BKR_OFF + 196;
constexpr int GBR_OFF  = GBC_OFF + 197;

constexpr int PREP_TOTAL = 24832+128+12416+64+8192+192+64+4096+64+8192+192+64+4096+64+4096+64+64+1+64+64+4096+64+6;
constexpr int PREP2_TOTAL = 25088 + 12544;

DEV float b2f(unsigned short u){ return __uint_as_float(((unsigned)u) << 16); }
DEV unsigned short f2b(float f){
    unsigned u = __float_as_uint(f);
    return (unsigned short)((u + 0x7fffu + ((u >> 16) & 1u)) >> 16);
}
DEV float blo(unsigned u){ return __uint_as_float(u << 16); }
DEV float bhi(unsigned u){ return __uint_as_float(u & 0xffff0000u); }
DEV int bcasti(int v, int k){ return __builtin_amdgcn_readlane(v, k); }
DEV float wave_sum(float v){
    #pragma unroll
    for (int off = 32; off > 0; off >>= 1) v += __shfl_xor(v, off, 64);
    return v;
}
DEV float ldv(const void* p, int i, bool isbf){
    return isbf ? b2f(((const unsigned short*)p)[i]) : ((const float*)p)[i];
}
DEV unsigned short ld16(const void* p, int i, bool isbf){
    return isbf ? ((const unsigned short*)p)[i] : f2b(((const float*)p)[i]);
}
DEV float sigm(float x){ return 1.f / (1.f + __expf(-x)); }

struct WPtrs {
    const void *ptW1, *ptb1, *ptW2, *ptb2;
    const void *pfW1, *pfb1, *pfW2, *pfb2;
    const void *zkW, *zkb, *rkW, *rkb, *cW, *cb;
    const void *eW1, *eb1, *eW2, *eb2;
    const void *dW1, *db1, *dW2, *db2;
};

// ---- dtype detection ----
__global__ __launch_bounds__(256) void detect_kernel(const void* y, float* __restrict__ ws){
    __shared__ int bad;
    if (threadIdx.x == 0) bad = 0;
    __syncthreads();
    const unsigned short* yy = (const unsigned short*)y;
    int mybad = 0;
    for (int i = threadIdx.x; i < 4096; i += 256){
        float v = b2f(yy[i]);
        if (!(v > -1.0e6f && v < 1.0e6f)) mybad = 1;
    }
    if (mybad) bad = 1;
    __syncthreads();
    if (threadIdx.x == 0) ws[FLAG_OFF] = bad ? 0.0f : 1.0f;
}

// ---- weight prep (pass 1) ----
__global__ __launch_bounds__(256) void prep_kernel(WPtrs P, float* __restrict__ ws){
    int j = blockIdx.x * 256 + threadIdx.x;
    if (j >= PREP_TOTAL) return;
    bool isbf = ws[FLAG_OFF] > 0.5f;
    if (j < 24832){
        int k = j >> 7, c = j & 127;
        ws[WZR_OFF+j] = (c < 64) ? ldv(P.zkW, k*64+c, isbf) : ldv(P.rkW, k*64+(c-64), isbf);
        return;
    } j -= 24832;
    if (j < 128){ ws[GB_OFF+j] = (j < 64) ? ldv(P.zkb, j, isbf) : ldv(P.rkb, j-64, isbf); return; } j -= 128;
    if (j < 12416){ ws[CW_OFF+j] = ldv(P.cW, j, isbf); return; } j -= 12416;
    if (j < 64){ ws[CB_OFF+j] = ldv(P.cb, j, isbf); return; } j -= 64;
    if (j < 8192){ ws[PT1_OFF+j] = ldv(P.ptW1, j, isbf); return; } j -= 8192;
    if (j < 192){ ws[AT_OFF+j] = ldv(P.ptW1, 128*64+j, isbf); return; } j -= 192;
    if (j < 64){ ws[BT1_OFF+j] = ldv(P.ptb1, j, isbf); return; } j -= 64;
    if (j < 4096){ ws[WT2_OFF+j] = ldv(P.ptW2, j, isbf); return; } j -= 4096;
    if (j < 64){ ws[BT2_OFF+j] = ldv(P.ptb2, j, isbf); return; } j -= 64;
    if (j < 8192){ ws[PF1_OFF+j] = ldv(P.pfW1, j, isbf); return; } j -= 8192;
    if (j < 192){ ws[AF_OFF+j] = ldv(P.pfW1, 128*64+j, isbf); return; } j -= 192;
    if (j < 64){ ws[BF1_OFF+j] = ldv(P.pfb1, j, isbf); return; } j -= 64;
    if (j < 4096){ ws[WF2_OFF+j] = ldv(P.pfW2, j, isbf); return; } j -= 4096;
    if (j < 64){ ws[BF2_OFF+j] = ldv(P.pfb2, j, isbf); return; } j -= 64;
    if (j < 4096){ ws[DW1_OFF+j] = ldv(P.dW1, j, isbf); return; } j -= 4096;
    if (j < 64){ ws[DW2_OFF+j] = ldv(P.dW2, j, isbf); return; } j -= 64;
    if (j < 64){ ws[DB1_OFF+j] = ldv(P.db1, j, isbf); return; } j -= 64;
    if (j < 1){ ws[DB2_OFF] = ldv(P.db2, 0, isbf); return; } j -= 1;
    if (j < 64){ ws[EW1_OFF+j] = ldv(P.eW1, j, isbf); return; } j -= 64;
    if (j < 64){ ws[EB1_OFF+j] = ldv(P.eb1, j, isbf); return; } j -= 64;
    if (j < 4096){ ws[EW2_OFF+j] = ldv(P.eW2, j, isbf); return; } j -= 4096;
    if (j < 64){ ws[EB2_OFF+j] = ldv(P.eb2, j, isbf); return; } j -= 64;
    ws[LOSS_OFF+j] = 0.f;
}

// ---- prep pass 2 ----
__global__ __launch_bounds__(256) void prep2_kernel(float* __restrict__ ws){
    int j = blockIdx.x * 256 + threadIdx.x;
    if (j >= PREP2_TOTAL) return;
    if (j < 25088){
        int r = j >> 7, c = j & 127;
        float v;
        if (r < 64) v = ws[WZR_OFF + r*128 + c];
        else if (r < 128){
            int h = r - 64; float s = 0.f;
            for (int m = 0; m < 64; m++)
                s = fmaf(ws[WT2_OFF + h*64 + m], ws[WZR_OFF + (64+m)*128 + c], s);
            v = s;
        } else if (r < 192){
            int h = r - 128; float s = 0.f;
            for (int m = 0; m < 64; m++)
                s = fmaf(ws[WF2_OFF + h*64 + m], ws[WZR_OFF + (128+m)*128 + c], s);
            v = s;
        } else if (r < 194) v = ws[WZR_OFF + r*128 + c];
        else if (r == 194){
            float s = 0.f;
            for (int m = 0; m < 64; m++)
                s = fmaf(ws[BT2_OFF + m], ws[WZR_OFF + (64+m)*128 + c], s);
            v = s;
        } else {
            float s = 0.f;
            for (int m = 0; m < 64; m++)
                s = fmaf(ws[BF2_OFF + m], ws[WZR_OFF + (128+m)*128 + c], s);
            v = s;
        }
        ws[NWZR_OFF + j] = v;
        return;
    }
    j -= 25088;
    {
        int r = j >> 6, c = j & 63;
        float v;
        if (r < 64) v = ws[CW_OFF + r*64 + c];
        else if (r < 128){
            int h = r - 64; float s = 0.f;
            for (int m = 0; m < 64; m++)
                s = fmaf(ws[WT2_OFF + h*64 + m], ws[CW_OFF + (64+m)*64 + c], s);
            v = s;
        } else if (r < 192){
            int h = r - 128; float s = 0.f;
            for (int m = 0; m < 64; m++)
                s = fmaf(ws[WF2_OFF + h*64 + m], ws[CW_OFF + (128+m)*64 + c], s);
            v = s;
        } else if (r < 194) v = ws[CW_OFF + r*64 + c];
        else if (r == 194){
            float s = 0.f;
            for (int m = 0; m < 64; m++)
                s = fmaf(ws[BT2_OFF + m], ws[CW_OFF + (64+m)*64 + c], s);
            v = s;
        } else {
            float s = 0.f;
            for (int m = 0; m < 64; m++)
                s = fmaf(ws[BF2_OFF + m], ws[CW_OFF + (128+m)*64 + c], s);
            v = s;
        }
        ws[NCW_OFF + j] = v;
    }
}

// ---- node setup ----
__global__ __launch_bounds__(256) void setup_node(const void* __restrict__ prb, float* __restrict__ ws){
    int i = blockIdx.x * 256 + threadIdx.x;
    if (i >= N) return;
    bool isbf = ws[FLAG_OFF] > 0.5f;
    ws[PRB0_OFF+i] = ldv(prb, 2*i,   isbf);
    ws[PRB1_OFF+i] = ldv(prb, 2*i+1, isbf);
    if (i < NBUK){
        int* wsI = (int*)ws;
        wsI[BKC_OFF+i] = 0; wsI[BKR_OFF+i] = 0;
    }
}

// ---- bucket histogram ----
__global__ __launch_bounds__(256) void bucket_hist(const int* __restrict__ ei, int* __restrict__ wsI){
    __shared__ int hc[NBUK], hr[NBUK];
    int t = threadIdx.x;
    for (int i = t; i < NBUK; i += 256){ hc[i] = 0; hr[i] = 0; }
    __syncthreads();
    int e0 = blockIdx.x * 4096;
    for (int i = 0; i < 16; i++){
        int e = e0 + i*256 + t;
        if (e < E){
            int r = ei[e], c = ei[E+e];
            if (r != c) atomicAdd(&hc[c >> 8], 1);
            atomicAdd(&hr[r >> 8], 1);
        }
    }
    __syncthreads();
    if (t < NBUK){
        if (hc[t]) atomicAdd(&wsI[BKC_OFF+t], hc[t]);
        if (hr[t]) atomicAdd(&wsI[BKR_OFF+t], hr[t]);
    }
}

// ---- bucket scan ----
__global__ __launch_bounds__(256) void bucket_scan(int* __restrict__ wsI){
    int y = blockIdx.y, t = threadIdx.x;
    const int* bk = wsI + (y ? BKR_OFF : BKC_OFF);
    int* gb = wsI + (y ? GBR_OFF : GBC_OFF);
    int* gf = wsI + (y ? GFR_OFF : GFC_OFF);
    __shared__ int sh[256];
    int v = (t < NBUK) ? bk[t] : 0;
    sh[t] = v;
    __syncthreads();
    #pragma unroll
    for (int off = 1; off < 256; off <<= 1){
        int u = (t >= (unsigned)off) ? sh[t - off] : 0;
        __syncthreads();
        sh[t] += u;
        __syncthreads();
    }
    int base = sh[t] - v;
    if (t < NBUK){ gb[t] = base; gf[t] = base; }
    if (t == NBUK - 1) gb[NBUK] = sh[t];
}

// ---- binned scatter phase A ----
__global__ __launch_bounds__(256) void scatter_binA(const int* __restrict__ ei,
                                                    const void* __restrict__ attr,
                                                    const void* __restrict__ aij,
                                                    float* __restrict__ ws){
    __shared__ int hc[NBUK], hr[NBUK], bc[NBUK], br[NBUK];
    int t = threadIdx.x;
    for (int i = t; i < NBUK; i += 256){ hc[i] = 0; hr[i] = 0; }
    __syncthreads();
    int* wsI = (int*)ws;
    int e0 = blockIdx.x * 4096;
    for (int i = 0; i < 16; i++){
        int e = e0 + i*256 + t;
        if (e < E){
            int r = ei[e], c = ei[E+e];
            if (r != c) atomicAdd(&hc[c >> 8], 1);
            atomicAdd(&hr[r >> 8], 1);
        }
    }
    __syncthreads();
    if (t < NBUK){
        bc[t] = atomicAdd(&wsI[GFC_OFF+t], hc[t]);
        br[t] = atomicAdd(&wsI[GFR_OFF+t], hr[t]);
        hc[t] = 0; hr[t] = 0;
    }
    __syncthreads();
    bool isbf = ws[FLAG_OFF] > 0.5f;
    uint4* cstg = (uint4*)(ws + CSTG_OFF);
    uint4* rstg = (uint4*)(ws + RSTG_OFF);
    for (int i = 0; i < 16; i++){
        int e = e0 + i*256 + t;
        if (e < E){
            int r = ei[e], c = ei[E+e];
            unsigned a0 = ld16(attr, 3*e, isbf), a1 = ld16(attr, 3*e+1, isbf);
            unsigned a2 = ld16(attr, 3*e+2, isbf), av = ld16(aij, e, isbf);
            unsigned a01 = a0 | (a1 << 16);
            if (r != c){
                int off = atomicAdd(&hc[c >> 8], 1);
                cstg[bc[c >> 8] + off] = make_uint4((unsigned)r | (a2 << 16), a01, (unsigned)c, 0u);
            }
            int off2 = atomicAdd(&hr[r >> 8], 1);
            rstg[br[r >> 8] + off2] = make_uint4((unsigned)c | (a2 << 16), a01, av << 16, (unsigned)r);
        }
    }
}

// ---- per-bucket degree count ----
__global__ __launch_bounds__(256) void deg_count(float* __restrict__ ws){
    __shared__ int cnt[256];
    __shared__ int scnt[256];
    int* wsI = (int*)ws;
    int b = blockIdx.x, t = threadIdx.x;
    cnt[t] = 0; scnt[t] = 0;
    __syncthreads();
    if (blockIdx.y == 0){
        int beg = wsI[GBC_OFF + b], end = wsI[GFC_OFF + b];
        const uint4* cstg = (const uint4*)(ws + CSTG_OFF);
        for (int p = beg + t; p < end; p += 256)
            atomicAdd(&cnt[(int)(cstg[p].z & 255u)], 1);
        __syncthreads();
        int node = b*256 + t;
        if (node < N) wsI[CDEG_OFF + node] = cnt[t];
    } else {
        int beg = wsI[GBR_OFF + b], end = wsI[GFR_OFF + b];
        const uint4* rstg = (const uint4*)(ws + RSTG_OFF);
        for (int p = beg + t; p < end; p += 256){
            uint4 q = rstg[p];
            int idx = (int)(q.w & 255u);
            atomicAdd(&cnt[idx], 1);
            if ((q.x & 0xffffu) == q.w) atomicAdd(&scnt[idx], 1);
        }
        __syncthreads();
        int node = b*256 + t;
        if (node < N){
            wsI[RDEG_OFF + node] = cnt[t];
            wsI[SDEG_OFF + node] = scnt[t];
        }
    }
}

DEV int deg_at(const int* wsI, int y, int i){
    if (y == 0) return wsI[CDEG_OFF+i];
    return wsI[RDEG_OFF+i];
}
__global__ __launch_bounds__(256) void scan1(int* __restrict__ wsI){
    int y = blockIdx.y;
    int* tmp = wsI + (y == 0 ? LCP_OFF : FRP_OFF);
    int i = blockIdx.x * 256 + threadIdx.x;
    __shared__ int sh[256];
    int v = (i < N) ? deg_at(wsI, y, i) : 0;
    sh[threadIdx.x] = v;
    __syncthreads();
    #pragma unroll
    for (int off = 1; off < 256; off <<= 1){
        int t = (threadIdx.x >= (unsigned)off) ? sh[threadIdx.x - off] : 0;
        __syncthreads();
        sh[threadIdx.x] += t;
        __syncthreads();
    }
    if (i < N) tmp[i] = sh[threadIdx.x] - v;
    if (threadIdx.x == 255) wsI[BS_OFF + y*256 + blockIdx.x] = sh[255];
}
__global__ __launch_bounds__(256) void scan2(int* __restrict__ wsI){
    int y = blockIdx.y, t = threadIdx.x;
    __shared__ int sh[256];
    int v = (t < 196) ? wsI[BS_OFF + y*256 + t] : 0;
    sh[t] = v;
    __syncthreads();
    #pragma unroll
    for (int off = 1; off < 256; off <<= 1){
        int u = (t >= (unsigned)off) ? sh[t - off] : 0;
        __syncthreads();
        sh[t] += u;
        __syncthreads();
    }
    wsI[BO_OFF + y*256 + t] = sh[t] - v;
}
__global__ __launch_bounds__(256) void scan3(int* __restrict__ wsI){
    int y = blockIdx.y;
    int* ptr = wsI + (y == 0 ? LCP_OFF : FRP_OFF);
    int i = blockIdx.x * 256 + threadIdx.x;
    if (i < N){
        int d = deg_at(wsI, y, i);
        int p = ptr[i] + wsI[BO_OFF + y*256 + blockIdx.x];
        ptr[i] = p;
        if (y == 0){
            wsI[LCF_OFF+i] = p;
            if (i == N-1) ptr[N] = p + d;
        } else {
            int live = wsI[RDEG_OFF+i] - wsI[SDEG_OFF+i];
            wsI[LRF_OFF+i] = p;
            wsI[LE_OFF+i]  = p + live;
            wsI[SFF_OFF+i] = p + live;
            if (i == N-1) ptr[N] = E;
        }
    }
}

// ---- binned scatter phase B ----
__global__ __launch_bounds__(256) void scatter_binB(float* __restrict__ ws){
    int* wsI = (int*)ws;
    int b = blockIdx.x;
    if (blockIdx.y == 0){
        int beg = wsI[GBC_OFF + b];
        int end = wsI[GFC_OFF + b];
        const uint4* cstg = (const uint4*)(ws + CSTG_OFF);
        uint2* crec = (uint2*)(ws + CREC_OFF);
        for (int p = beg + threadIdx.x; p < end; p += 256){
            uint4 q = cstg[p];
            int d = atomicAdd(&wsI[LCF_OFF + (int)q.z], 1);
            crec[d] = make_uint2(q.x, q.y);
        }
    } else {
        int beg = wsI[GBR_OFF + b];
        int end = wsI[GFR_OFF + b];
        const uint4* rstg = (const uint4*)(ws + RSTG_OFF);
        uint4* rrec = (uint4*)(ws + RREC_OFF);
        for (int p = beg + threadIdx.x; p < end; p += 256){
            uint4 q = rstg[p];
            int r = (int)q.w;
            int c = (int)(q.x & 0xffffu);
            int d = (r != c) ? atomicAdd(&wsI[LRF_OFF + r], 1)
                             : atomicAdd(&wsI[SFF_OFF + r], 1);
            rrec[d] = make_uint4(q.x, q.y, q.z, 0u);
        }
    }
}

// ---- encoder ----
__global__ __launch_bounds__(256) void encode_init(const void* __restrict__ x,
                                                   float* __restrict__ ws){
    int node = blockIdx.x * 256 + threadIdx.x;
    if (node >= N) return;
    bool isbf = ws[FLAG_OFF] > 0.5f;
    int j0 = blockIdx.y * 32;
    float xv = ldv(x, node, isbf);
    float acc[32];
    #pragma unroll
    for (int j = 0; j < 32; j++) acc[j] = ws[EB2_OFF + j0 + j];
    for (int k = 0; k < 64; k++){
        float t = fmaxf(fmaf(xv, ws[EW1_OFF+k], ws[EB1_OFF+k]), 0.f);
        const float* wr = ws + EW2_OFF + (size_t)k*64 + j0;
        #pragma unroll
        for (int j = 0; j < 32; j++) acc[j] = fmaf(t, wr[j], acc[j]);
    }
    unsigned short* hb = (unsigned short*)(ws + HB_OFF);
    #pragma unroll
    for (int j = 0; j < 32; j++){
        ws[H0F_OFF + (size_t)(j0+j)*N + node] = acc[j];
        ws[HF_OFF  + (size_t)(j0+j)*N + node] = acc[j];
        hb[(size_t)(j0+j)*N + node] = f2b(acc[j]);
    }
}

// ---- first-layer precompute, LDS weight tile [128][32] ----
__global__ __launch_bounds__(256) void node_pre(float* __restrict__ ws){
    __shared__ float sW[128*32];
    int dir = blockIdx.y >> 1, tl = blockIdx.y & 1;
    int j0 = tl * 32;
    {
        const float* W1 = ws + (dir ? PF1_OFF : PT1_OFF);
        for (int i = threadIdx.x; i < 128*32; i += 256){
            int r = i >> 5, jj = i & 31;
            sW[i] = W1[(size_t)r*64 + j0 + jj];
        }
    }
    __syncthreads();
    int node = blockIdx.x * 256 + threadIdx.x;
    if (node >= N) return;
    float* paOut = ws + (dir ? PAF_OFF : PAT_OFF);
    unsigned short* pbOut = (unsigned short*)(ws + (dir ? PBF_OFF : PBT_OFF));
    const unsigned short* hb = (const unsigned short*)(ws + HB_OFF);
    float aA[32], aB[32];
    #pragma unroll
    for (int j = 0; j < 32; j++){ aA[j] = 0.f; aB[j] = 0.f; }
    #pragma unroll 4
    for (int k = 0; k < 64; k++){
        float hv = b2f(hb[(size_t)k*N + node]);
        const float* wA = sW + k*32;
        const float* wB = sW + (64+k)*32;
        #pragma unroll
        for (int j = 0; j < 32; j++){
            aA[j] = fmaf(hv, wA[j], aA[j]);
            aB[j] = fmaf(hv, wB[j], aB[j]);
        }
    }
    #pragma unroll
    for (int j = 0; j < 32; j++){
        paOut[(size_t)node*64 + j0 + j] = aA[j];
        pbOut[(size_t)node*64 + j0 + j] = f2b(aB[j]);
    }
}

// ---- CSR message gather ----
template<int DIR>
__global__ __launch_bounds__(256) void gather_msgs(float* __restrict__ ws){
    const int* wsI = (const int*)ws;
    float* pa = ws + (DIR ? PAF_OFF : PAT_OFF);
    const unsigned short* pgb = (const unsigned short*)(ws + (DIR ? PBF_OFF : PBT_OFF));
    const float* A3 = ws + (DIR ? AF_OFF : AT_OFF);
    const float* b1 = ws + (DIR ? BF1_OFF : BT1_OFF);

    int lane = threadIdx.x & 63;
    int wv = threadIdx.x >> 6;
    float A0 = A3[lane], A1 = A3[64+lane], A2 = A3[128+lane];
    float B1 = b1[lane];
    int gw = blockIdx.x * 4 + wv;
    int nw = gridDim.x * 4;
    for (int node = gw; node < N; node += nw){
        float pav = pa[(size_t)node*64 + lane] + B1;
        float hs = 0.f;
        int beg, end;
        if (DIR == 0){ beg = wsI[LCP_OFF+node]; end = wsI[LCP_OFF+node+1]; }
        else         { beg = wsI[FRP_OFF+node]; end = wsI[LE_OFF+node]; }
        int cnt = end - beg;
        for (int base = beg; base < end; base += 64){
            int mcnt = end - base; if (mcnt > 64) mcnt = 64;
            unsigned rxL = 0, ryL = 0;
            if (lane < mcnt){
                if (DIR == 0){
                    uint2 q = ((const uint2*)(ws + CREC_OFF))[base + lane];
                    rxL = q.x; ryL = q.y;
                } else {
                    uint4 q = ((const uint4*)(ws + RREC_OFF))[base + lane];
                    rxL = q.x; ryL = q.y;
                }
            }
            for (int g = 0; g < mcnt; g += 8){
                unsigned rxa[8], rya[8];
                float pb[8];
                #pragma unroll
                for (int t = 0; t < 8; t++){
                    rxa[t] = (unsigned)bcasti((int)rxL, g+t);
                    rya[t] = (unsigned)bcasti((int)ryL, g+t);
                    int o = (int)(rxa[t] & 0xffffu);
                    float pv = b2f(pgb[(size_t)o*64 + lane]);
                    pb[t] = (g+t < mcnt) ? pv : -3.0e38f;
                }
                #pragma unroll
                for (int t = 0; t < 8; t++){
                    float hv = fmaf(blo(rya[t]), A0,
                               fmaf(bhi(rya[t]), A1,
                               fmaf(bhi(rxa[t]), A2, pav))) + pb[t];
                    hs += fmaxf(hv, 0.f);
                }
            }
        }
        pa[(size_t)node*64 + lane] = hs;
        if (lane == 0) ws[CNT_OFF + DIR*N + node] = (float)cnt;
    }
}

// ---- transpose hs ----
__global__ __launch_bounds__(256) void transpose_msg(float* __restrict__ ws){
    __shared__ float t[64][65];
    const float* src = ws + (blockIdx.y ? PAF_OFF : PAT_OFF);
    unsigned short* dst = (unsigned short*)(ws + (blockIdx.y ? MFF_OFF : MTF_OFF));
    int n0 = blockIdx.x * 64;
    #pragma unroll
    for (int i = 0; i < 16; i++){
        int idx = i*256 + threadIdx.x;
        int nl = idx >> 6, f = idx & 63;
        int node = n0 + nl;
        t[nl][f] = (node < N) ? src[(size_t)node*64 + f] : 0.f;
    }
    __syncthreads();
    #pragma unroll
    for (int i = 0; i < 16; i++){
        int idx = i*256 + threadIdx.x;
        int fw = idx >> 6, nl = idx & 63;
        int node = n0 + nl;
        if (node < N) dst[(size_t)fw*N + node] = f2b(t[nl][fw]);
    }
}

// ---- gate z+r: LDS weight tile [196][32] (z cols 0..15 | r cols 16..31) ----
__global__ __launch_bounds__(256) void gate_zr(float* __restrict__ ws){
    __shared__ float sW[196*32];
    int tl = blockIdx.y, j0 = tl * 16;
    {
        const float* W = ws + NWZR_OFF;
        for (int i = threadIdx.x; i < 196*32; i += 256){
            int r = i >> 5, jj = i & 31;
            int col = (jj < 16) ? (j0 + jj) : (64 + j0 + (jj - 16));
            sW[i] = W[(size_t)r*128 + col];
        }
    }
    __syncthreads();
    int node = blockIdx.x * 256 + threadIdx.x;
    if (node >= N) return;
    const unsigned short* hb  = (const unsigned short*)(ws + HB_OFF);
    const unsigned short* mtU = (const unsigned short*)(ws + MTF_OFF);
    const unsigned short* mfU = (const unsigned short*)(ws + MFF_OFF);
    float p0 = ws[PRB0_OFF+node], p1 = ws[PRB1_OFF+node];
    float cT = ws[CNT_OFF+node], cF = ws[CNT_OFF+N+node];
    float az[16], ar[16];
    #pragma unroll
    for (int j = 0; j < 16; j++){
        az[j] = ws[GB_OFF + j0 + j]
              + p0*sW[192*32+j] + p1*sW[193*32+j] + cT*sW[194*32+j] + cF*sW[195*32+j];
        ar[j] = ws[GB_OFF + 64 + j0 + j]
              + p0*sW[192*32+16+j] + p1*sW[193*32+16+j] + cT*sW[194*32+16+j] + cF*sW[195*32+16+j];
    }
    #pragma unroll 4
    for (int k = 0; k < 64; k++){
        float aH = b2f(hb [(size_t)k*N + node]);
        float aT = b2f(mtU[(size_t)k*N + node]);
        float aF = b2f(mfU[(size_t)k*N + node]);
        const float* wH = sW + k*32;
        const float* wT = sW + (64+k)*32;
        const float* wF = sW + (128+k)*32;
        #pragma unroll
        for (int j = 0; j < 16; j++){
            az[j] = fmaf(aH, wH[j], fmaf(aT, wT[j], fmaf(aF, wF[j], az[j])));
            ar[j] = fmaf(aH, wH[16+j], fmaf(aT, wT[16+j], fmaf(aF, wF[16+j], ar[j])));
        }
    }
    unsigned short* RH = (unsigned short*)(ws + RH_OFF);
    #pragma unroll
    for (int j = 0; j < 16; j++){
        size_t off = (size_t)(j0+j)*N + node;
        ws[AL_OFF + off] = sigm(az[j]);
        RH[off] = f2b(sigm(ar[j]) * b2f(hb[off]));
    }
}

// ---- gate corr + update: LDS weight tile [196][16] ----
__global__ __launch_bounds__(256) void gate_corr(const int* __restrict__ tags,
                                                 float* __restrict__ ws){
    __shared__ float sW[196*16];
    int tl = blockIdx.y, j0 = tl*16;
    {
        const float* W = ws + NCW_OFF;
        for (int i = threadIdx.x; i < 196*16; i += 256){
            int r = i >> 4, jj = i & 15;
            sW[i] = W[(size_t)r*64 + j0 + jj];
        }
    }
    __syncthreads();
    int node = blockIdx.x * 256 + threadIdx.x;
    if (node >= N) return;
    const unsigned short* RH  = (const unsigned short*)(ws + RH_OFF);
    const unsigned short* mtU = (const unsigned short*)(ws + MTF_OFF);
    const unsigned short* mfU = (const unsigned short*)(ws + MFF_OFF);
    float p0 = ws[PRB0_OFF+node], p1 = ws[PRB1_OFF+node];
    float cT = ws[CNT_OFF+node], cF = ws[CNT_OFF+N+node];
    float acc[16];
    #pragma unroll
    for (int j = 0; j < 16; j++)
        acc[j] = ws[CB_OFF + j0 + j]
               + p0*sW[192*16+j] + p1*sW[193*16+j] + cT*sW[194*16+j] + cF*sW[195*16+j];
    #pragma unroll 4
    for (int k = 0; k < 64; k++){
        float aR = b2f(RH [(size_t)k*N + node]);
        float aT = b2f(mtU[(size_t)k*N + node]);
        float aF = b2f(mfU[(size_t)k*N + node]);
        const float* wR = sW + k*16;
        const float* wT = sW + (64+k)*16;
        const float* wF = sW + (128+k)*16;
        #pragma unroll
        for (int j = 0; j < 16; j++)
            acc[j] = fmaf(aR, wR[j], fmaf(aT, wT[j], fmaf(aF, wF[j], acc[j])));
    }
    int tg = tags[node];
    unsigned short* hb = (unsigned short*)(ws + HB_OFF);
    #pragma unroll
    for (int j = 0; j < 16; j++){
        size_t off = (size_t)(j0+j)*N + node;
        float hn = fmaf(ws[AL_OFF+off], tanhf(acc[j]), ws[HF_OFF+off]);
        if (tg == 1) hn = ws[H0F_OFF+off];
        ws[HF_OFF+off] = hn;
        hb[off] = f2b(hn);
    }
}

// ---- decode stage 1, LDS DW1 tile [64][32]; bf16 src -> f32 dst ----
__global__ __launch_bounds__(256) void dec1hf(const unsigned short* __restrict__ src,
                                              float* __restrict__ dst,
                                              float* __restrict__ ws){
    __shared__ float sW[64*32];
    int j0 = blockIdx.y * 32;
    for (int i = threadIdx.x; i < 64*32; i += 256){
        int r = i >> 5, jj = i & 31;
        sW[i] = ws[DW1_OFF + (size_t)r*64 + j0 + jj];
    }
    __syncthreads();
    int node = blockIdx.x * 256 + threadIdx.x;
    if (node >= N) return;
    float acc[32];
    #pragma unroll
    for (int j = 0; j < 32; j++) acc[j] = ws[DB1_OFF + j0 + j];
    #pragma unroll 4
    for (int k = 0; k < 64; k++){
        float a = b2f(src[(size_t)k*N + node]);
        const float* wr = sW + k*32;
        #pragma unroll
        for (int j = 0; j < 32; j++) acc[j] = fmaf(a, wr[j], acc[j]);
    }
    #pragma unroll
    for (int j = 0; j < 32; j++)
        dst[(size_t)(j0+j)*N + node] = fmaxf(acc[j], 0.f);
}

// ---- decode stage 1, LDS DW1 tile; bf16 src -> bf16 dst ----
__global__ __launch_bounds__(256) void dec1hb(const unsigned short* __restrict__ src,
                                              unsigned short* __restrict__ dst,
                                              float* __restrict__ ws){
    __shared__ float sW[64*32];
    int j0 = blockIdx.y * 32;
    for (int i = threadIdx.x; i < 64*32; i += 256){
        int r = i >> 5, jj = i & 31;
        sW[i] = ws[DW1_OFF + (size_t)r*64 + j0 + jj];
    }
    __syncthreads();
    int node = blockIdx.x * 256 + threadIdx.x;
    if (node >= N) return;
    float acc[32];
    #pragma unroll
    for (int j = 0; j < 32; j++) acc[j] = ws[DB1_OFF + j0 + j];
    #pragma unroll 4
    for (int k = 0; k < 64; k++){
        float a = b2f(src[(size_t)k*N + node]);
        const float* wr = sW + k*32;
        #pragma unroll
        for (int j = 0; j < 32; j++) acc[j] = fmaf(a, wr[j], acc[j]);
    }
    #pragma unroll
    for (int j = 0; j < 32; j++)
        dst[(size_t)(j0+j)*N + node] = f2b(fmaxf(acc[j], 0.f));
}

// ---- decode stage 2 + encode(u) + enc loss; LDS EW2 tile + DW2/EW1/EB1 ----
__global__ __launch_bounds__(256) void enc_u(int step, float* __restrict__ ws){
    __shared__ float sW[64*32];
    __shared__ float sDW2[64], sEW1[64], sEB1[64];
    int j0 = blockIdx.y * 32;
    for (int i = threadIdx.x; i < 64*32; i += 256){
        int r = i >> 5, jj = i & 31;
        sW[i] = ws[EW2_OFF + (size_t)r*64 + j0 + jj];
    }
    if (threadIdx.x < 64){
        sDW2[threadIdx.x] = ws[DW2_OFF + threadIdx.x];
        sEW1[threadIdx.x] = ws[EW1_OFF + threadIdx.x];
        sEB1[threadIdx.x] = ws[EB1_OFF + threadIdx.x];
    }
    __syncthreads();
    int node = blockIdx.x * 256 + threadIdx.x;
    float encA = 0.f;
    if (node < N){
        float u = ws[DB2_OFF];
        #pragma unroll 4
        for (int j = 0; j < 64; j++)
            u = fmaf(ws[T1_OFF + (size_t)j*N + node], sDW2[j], u);
        if (blockIdx.y == 0) ws[UV_OFF+node] = u;
        float acc[32];
        #pragma unroll
        for (int j = 0; j < 32; j++) acc[j] = ws[EB2_OFF + j0 + j];
        for (int k = 0; k < 64; k++){
            float t = fmaxf(fmaf(u, sEW1[k], sEB1[k]), 0.f);
            const float* wr = sW + k*32;
            #pragma unroll
            for (int j = 0; j < 32; j++) acc[j] = fmaf(t, wr[j], acc[j]);
        }
        unsigned short* ev = (unsigned short*)(ws + EV_OFF);
        #pragma unroll
        for (int j = 0; j < 32; j++){
            size_t off = (size_t)(j0+j)*N + node;
            ev[off] = f2b(acc[j]);
            float d = acc[j] - ws[HF_OFF+off];
            encA += d*d;
        }
    }
    encA = wave_sum(encA);
    if ((threadIdx.x & 63) == 0) atomicAdd(&ws[LOSS_OFF + step*3 + 1], encA);
}

// ---- final: u2 = dec(E) (bf16 T1), auto loss, residual, res loss ----
__global__ __launch_bounds__(256) void aux_res(int step, const void* __restrict__ y,
                                               float* __restrict__ ws){
    __shared__ float sDW2[64];
    if (threadIdx.x < 64) sDW2[threadIdx.x] = ws[DW2_OFF + threadIdx.x];
    __syncthreads();
    const int* wsI = (const int*)ws;
    int node = blockIdx.x * 256 + threadIdx.x;
    bool isbf = ws[FLAG_OFF] > 0.5f;
    float autoA = 0.f, resA = 0.f;
    if (node < N){
        const unsigned short* T1u = (const unsigned short*)(ws + T1_OFF);
        float u2 = ws[DB2_OFF];
        #pragma unroll 4
        for (int j = 0; j < 64; j++)
            u2 = fmaf(b2f(T1u[(size_t)j*N + node]), sDW2[j], u2);
        float u = ws[UV_OFF+node];
        float ad = u2 - u;
        autoA = ad*ad;
        float acc = 0.f;
        int beg = wsI[FRP_OFF+node], end = wsI[FRP_OFF+node+1];
        const uint4* rrec = (const uint4*)(ws + RREC_OFF);
        for (int p = beg; p < end; p++){
            uint4 q = rrec[p];
            acc = fmaf(bhi(q.z), ws[UV_OFF + (int)(q.x & 0xffffu)], acc);
        }
        float d = acc - ldv(y, node, isbf);
        resA = d*d;
    }
    autoA = wave_sum(autoA);
    resA = wave_sum(resA);
    if ((threadIdx.x & 63) == 0){
        atomicAdd(&ws[LOSS_OFF + step*3 + 2], autoA);
        atomicAdd(&ws[LOSS_OFF + step*3], resA);
    }
}

// ---- output writer ----
__global__ __launch_bounds__(256) void write_out(void* __restrict__ outp,
                                                 const float* __restrict__ ws){
    int i = blockIdx.x * 256 + threadIdx.x;
    if (i > N) return;
    bool isbf = ws[FLAG_OFF] > 0.5f;
    float v;
    if (i < N){
        v = ws[UV_OFF+i];
    } else {
        const float* L = ws + LOSS_OFF;
        float inv = 1.f / (float)N, invl = 1.f / ((float)N * 64.f);
        v = 0.9f*L[0]*inv + L[1]*invl + L[2]*inv
          +      L[3]*inv + L[4]*invl + L[5]*inv;
    }
    if (isbf) ((unsigned short*)outp)[i] = f2b(v);
    else      ((float*)outp)[i] = v;
}

extern "C" void kernel_launch(void* const* d_in, const int* in_sizes, int n_in,
                              void* d_out, int out_size, void* d_ws, size_t ws_size,
                              hipStream_t stream){
    const void* x    = d_in[0];
    const void* y    = d_in[2];
    const int* tags  = (const int*)d_in[3];
    const int* ei    = (const int*)d_in[4];
    const void* attr = d_in[5];
    const void* aij  = d_in[6];
    const void* prb  = d_in[7];
    WPtrs P;
    P.ptW1 = d_in[8];  P.ptb1 = d_in[9];  P.ptW2 = d_in[10]; P.ptb2 = d_in[11];
    P.pfW1 = d_in[12]; P.pfb1 = d_in[13]; P.pfW2 = d_in[14]; P.pfb2 = d_in[15];
    P.zkW  = d_in[16]; P.zkb  = d_in[17]; P.rkW  = d_in[18]; P.rkb  = d_in[19];
    P.cW   = d_in[20]; P.cb   = d_in[21];
    P.eW1  = d_in[22]; P.eb1  = d_in[23]; P.eW2  = d_in[24]; P.eb2  = d_in[25];
    P.dW1  = d_in[26]; P.db1  = d_in[27]; P.dW2  = d_in[28]; P.db2  = d_in[29];
    float* ws = (float*)d_ws;
    int* wsI = (int*)d_ws;

    detect_kernel<<<1, 256, 0, stream>>>(y, ws);
    prep_kernel<<<(PREP_TOTAL + 255)/256, 256, 0, stream>>>(P, ws);
    prep2_kernel<<<(PREP2_TOTAL + 255)/256, 256, 0, stream>>>(ws);
    setup_node<<<196, 256, 0, stream>>>(prb, ws);
    bucket_hist<<<196, 256, 0, stream>>>(ei, wsI);
    bucket_scan<<<dim3(1, 2), 256, 0, stream>>>(wsI);
    scatter_binA<<<196, 256, 0, stream>>>(ei, attr, aij, ws);
    deg_count<<<dim3(196, 2), 256, 0, stream>>>(ws);
    scan1<<<dim3(196, 2), 256, 0, stream>>>(wsI);
    scan2<<<dim3(1, 2), 256, 0, stream>>>(wsI);
    scan3<<<dim3(196, 2), 256, 0, stream>>>(wsI);
    scatter_binB<<<dim3(196, 2), 256, 0, stream>>>(ws);
    encode_init<<<dim3(196, 2), 256, 0, stream>>>(x, ws);
    unsigned short* hb = (unsigned short*)(ws + HB_OFF);
    unsigned short* ev = (unsigned short*)(ws + EV_OFF);
    for (int step = 0; step < 2; step++){
        node_pre<<<dim3(196, 4), 256, 0, stream>>>(ws);
        gather_msgs<0><<<2048, 256, 0, stream>>>(ws);
        gather_msgs<1><<<2048, 256, 0, stream>>>(ws);
        transpose_msg<<<dim3(782, 2), 256, 0, stream>>>(ws);
        gate_zr<<<dim3(196, 4), 256, 0, stream>>>(ws);
        gate_corr<<<dim3(196, 4), 256, 0, stream>>>(tags, ws);
        dec1hf<<<dim3(196, 2), 256, 0, stream>>>(hb, ws + T1_OFF, ws);
        enc_u<<<dim3(196, 2), 256, 0, stream>>>(step, ws);
        dec1hb<<<dim3(196, 2), 256, 0, stream>>>(ev, (unsigned short*)(ws + T1_OFF), ws);
        aux_res<<<196, 256, 0, stream>>>(step, y, ws);
    }
    write_out<<<197, 256, 0, stream>>>(d_out, ws);
}

// Round 16
// 924.614 us; speedup vs baseline: 1.0299x; 1.0299x over previous
//
#include <hip/hip_runtime.h>

#define DEV __device__ __forceinline__

constexpr int N = 50000;
constexpr int E = 800000;
constexpr int NBUK = 196;

// ---- float region (4-byte units) ----
constexpr int HF_OFF  = 0;
constexpr int H0F_OFF = 64*N;
constexpr int MTF_OFF = 128*N;              // packed mt|mf uint [64][N] after transpose (aliased PBT/PBF before)
constexpr int MFF_OFF = 160*N;
constexpr int PBT_OFF = MTF_OFF;
constexpr int PBF_OFF = MFF_OFF;
constexpr int MP_OFF  = MTF_OFF;            // uint[64][N]
constexpr int R1_OFF  = 192*N;
constexpr int PAT_OFF = R1_OFF;
constexpr int PAF_OFF = R1_OFF + 64*N;
constexpr int AL_OFF  = R1_OFF;
constexpr int RH_OFF  = R1_OFF + 64*N;
constexpr int T1_OFF  = R1_OFF;
constexpr int EV_OFF  = R1_OFF + 64*N;
constexpr int CSTG_OFF = R1_OFF;
constexpr int RSTG_OFF = R1_OFF + 4*E;
constexpr int HB_OFF   = 352*N;
constexpr int UV_OFF   = 384*N;
constexpr int LOSS_OFF = UV_OFF + N;
constexpr int FLAG_OFF = LOSS_OFF + 7;
constexpr int WZR_OFF = LOSS_OFF + 8;
constexpr int GB_OFF  = WZR_OFF + 24832;
constexpr int CW_OFF  = GB_OFF + 128;
constexpr int CB_OFF  = CW_OFF + 12416;
constexpr int PT1_OFF = CB_OFF + 64;
constexpr int AT_OFF  = PT1_OFF + 8192;
constexpr int BT1_OFF = AT_OFF + 192;
constexpr int WT2_OFF = BT1_OFF + 64;
constexpr int BT2_OFF = WT2_OFF + 4096;
constexpr int PF1_OFF = BT2_OFF + 64;
constexpr int AF_OFF  = PF1_OFF + 8192;
constexpr int BF1_OFF = AF_OFF + 192;
constexpr int WF2_OFF = BF1_OFF + 64;
constexpr int BF2_OFF = WF2_OFF + 4096;
constexpr int DW1_OFF = BF2_OFF + 64;
constexpr int DW2_OFF = DW1_OFF + 4096;
constexpr int DB1_OFF = DW2_OFF + 64;
constexpr int DB2_OFF = DB1_OFF + 64;
constexpr int EW1_OFF = DB2_OFF + 4;
constexpr int EB1_OFF = EW1_OFF + 64;
constexpr int EW2_OFF = EB1_OFF + 64;
constexpr int EB2_OFF = EW2_OFF + 4096;
constexpr int PRB0_OFF = EB2_OFF + 64;
constexpr int PRB1_OFF = PRB0_OFF + N;
constexpr int NWZR_OFF = PRB1_OFF + N;      // 196*128
constexpr int NCW_OFF  = NWZR_OFF + 25088;  // 196*64
constexpr int CNT_OFF  = NCW_OFF + 12544;   // 2N
constexpr int FEND     = CNT_OFF + 2*N;
constexpr int CREC_OFF = FEND;
constexpr int RREC_OFF = CREC_OFF + 2*E;
constexpr int LCP_OFF  = RREC_OFF + 4*E;
constexpr int FRP_OFF  = LCP_OFF + N + 1;
constexpr int LE_OFF   = FRP_OFF + N + 1;
constexpr int LCF_OFF  = LE_OFF + N;
constexpr int LRF_OFF  = LCF_OFF + N;
constexpr int SFF_OFF  = LRF_OFF + N;
constexpr int CDEG_OFF = SFF_OFF + N;
constexpr int RDEG_OFF = CDEG_OFF + N;
constexpr int SDEG_OFF = RDEG_OFF + N;
constexpr int BS_OFF   = SDEG_OFF + N;
constexpr int BO_OFF   = BS_OFF + 512;
constexpr int GFC_OFF  = BO_OFF + 512;
constexpr int GFR_OFF  = GFC_OFF + 196;
constexpr int BKC_OFF  = GFR_OFF + 196;
constexpr int BKR_OFF  = BKC_OFF + 196;
constexpr int GBC_OFF  = BKR_OFF + 196;
constexpr int GBR_OFF  = GBC_OFF + 197;

constexpr int PREP_TOTAL = 24832+128+12416+64+8192+192+64+4096+64+8192+192+64+4096+64+4096+64+64+1+64+64+4096+64+6;
constexpr int PREP2_TOTAL = 25088 + 12544;

DEV float b2f(unsigned short u){ return __uint_as_float(((unsigned)u) << 16); }
DEV unsigned short f2b(float f){
    unsigned u = __float_as_uint(f);
    return (unsigned short)((u + 0x7fffu + ((u >> 16) & 1u)) >> 16);
}
DEV float blo(unsigned u){ return __uint_as_float(u << 16); }
DEV float bhi(unsigned u){ return __uint_as_float(u & 0xffff0000u); }
DEV int bcasti(int v, int k){ return __builtin_amdgcn_readlane(v, k); }
DEV float wave_sum(float v){
    #pragma unroll
    for (int off = 32; off > 0; off >>= 1) v += __shfl_xor(v, off, 64);
    return v;
}
DEV float ldv(const void* p, int i, bool isbf){
    return isbf ? b2f(((const unsigned short*)p)[i]) : ((const float*)p)[i];
}
DEV unsigned short ld16(const void* p, int i, bool isbf){
    return isbf ? ((const unsigned short*)p)[i] : f2b(((const float*)p)[i]);
}
DEV float sigm(float x){ return 1.f / (1.f + __expf(-x)); }

struct WPtrs {
    const void *ptW1, *ptb1, *ptW2, *ptb2;
    const void *pfW1, *pfb1, *pfW2, *pfb2;
    const void *zkW, *zkb, *rkW, *rkb, *cW, *cb;
    const void *eW1, *eb1, *eW2, *eb2;
    const void *dW1, *db1, *dW2, *db2;
};

// ---- dtype detection ----
__global__ __launch_bounds__(256) void detect_kernel(const void* y, float* __restrict__ ws){
    __shared__ int bad;
    if (threadIdx.x == 0) bad = 0;
    __syncthreads();
    const unsigned short* yy = (const unsigned short*)y;
    int mybad = 0;
    for (int i = threadIdx.x; i < 4096; i += 256){
        float v = b2f(yy[i]);
        if (!(v > -1.0e6f && v < 1.0e6f)) mybad = 1;
    }
    if (mybad) bad = 1;
    __syncthreads();
    if (threadIdx.x == 0) ws[FLAG_OFF] = bad ? 0.0f : 1.0f;
}

// ---- weight prep (pass 1) ----
__global__ __launch_bounds__(256) void prep_kernel(WPtrs P, float* __restrict__ ws){
    int j = blockIdx.x * 256 + threadIdx.x;
    if (j >= PREP_TOTAL) return;
    bool isbf = ws[FLAG_OFF] > 0.5f;
    if (j < 24832){
        int k = j >> 7, c = j & 127;
        ws[WZR_OFF+j] = (c < 64) ? ldv(P.zkW, k*64+c, isbf) : ldv(P.rkW, k*64+(c-64), isbf);
        return;
    } j -= 24832;
    if (j < 128){ ws[GB_OFF+j] = (j < 64) ? ldv(P.zkb, j, isbf) : ldv(P.rkb, j-64, isbf); return; } j -= 128;
    if (j < 12416){ ws[CW_OFF+j] = ldv(P.cW, j, isbf); return; } j -= 12416;
    if (j < 64){ ws[CB_OFF+j] = ldv(P.cb, j, isbf); return; } j -= 64;
    if (j < 8192){ ws[PT1_OFF+j] = ldv(P.ptW1, j, isbf); return; } j -= 8192;
    if (j < 192){ ws[AT_OFF+j] = ldv(P.ptW1, 128*64+j, isbf); return; } j -= 192;
    if (j < 64){ ws[BT1_OFF+j] = ldv(P.ptb1, j, isbf); return; } j -= 64;
    if (j < 4096){ ws[WT2_OFF+j] = ldv(P.ptW2, j, isbf); return; } j -= 4096;
    if (j < 64){ ws[BT2_OFF+j] = ldv(P.ptb2, j, isbf); return; } j -= 64;
    if (j < 8192){ ws[PF1_OFF+j] = ldv(P.pfW1, j, isbf); return; } j -= 8192;
    if (j < 192){ ws[AF_OFF+j] = ldv(P.pfW1, 128*64+j, isbf); return; } j -= 192;
    if (j < 64){ ws[BF1_OFF+j] = ldv(P.pfb1, j, isbf); return; } j -= 64;
    if (j < 4096){ ws[WF2_OFF+j] = ldv(P.pfW2, j, isbf); return; } j -= 4096;
    if (j < 64){ ws[BF2_OFF+j] = ldv(P.pfb2, j, isbf); return; } j -= 64;
    if (j < 4096){ ws[DW1_OFF+j] = ldv(P.dW1, j, isbf); return; } j -= 4096;
    if (j < 64){ ws[DW2_OFF+j] = ldv(P.dW2, j, isbf); return; } j -= 64;
    if (j < 64){ ws[DB1_OFF+j] = ldv(P.db1, j, isbf); return; } j -= 64;
    if (j < 1){ ws[DB2_OFF] = ldv(P.db2, 0, isbf); return; } j -= 1;
    if (j < 64){ ws[EW1_OFF+j] = ldv(P.eW1, j, isbf); return; } j -= 64;
    if (j < 64){ ws[EB1_OFF+j] = ldv(P.eb1, j, isbf); return; } j -= 64;
    if (j < 4096){ ws[EW2_OFF+j] = ldv(P.eW2, j, isbf); return; } j -= 4096;
    if (j < 64){ ws[EB2_OFF+j] = ldv(P.eb2, j, isbf); return; } j -= 64;
    ws[LOSS_OFF+j] = 0.f;
}

// ---- prep pass 2 ----
__global__ __launch_bounds__(256) void prep2_kernel(float* __restrict__ ws){
    int j = blockIdx.x * 256 + threadIdx.x;
    if (j >= PREP2_TOTAL) return;
    if (j < 25088){
        int r = j >> 7, c = j & 127;
        float v;
        if (r < 64) v = ws[WZR_OFF + r*128 + c];
        else if (r < 128){
            int h = r - 64; float s = 0.f;
            for (int m = 0; m < 64; m++)
                s = fmaf(ws[WT2_OFF + h*64 + m], ws[WZR_OFF + (64+m)*128 + c], s);
            v = s;
        } else if (r < 192){
            int h = r - 128; float s = 0.f;
            for (int m = 0; m < 64; m++)
                s = fmaf(ws[WF2_OFF + h*64 + m], ws[WZR_OFF + (128+m)*128 + c], s);
            v = s;
        } else if (r < 194) v = ws[WZR_OFF + r*128 + c];
        else if (r == 194){
            float s = 0.f;
            for (int m = 0; m < 64; m++)
                s = fmaf(ws[BT2_OFF + m], ws[WZR_OFF + (64+m)*128 + c], s);
            v = s;
        } else {
            float s = 0.f;
            for (int m = 0; m < 64; m++)
                s = fmaf(ws[BF2_OFF + m], ws[WZR_OFF + (128+m)*128 + c], s);
            v = s;
        }
        ws[NWZR_OFF + j] = v;
        return;
    }
    j -= 25088;
    {
        int r = j >> 6, c = j & 63;
        float v;
        if (r < 64) v = ws[CW_OFF + r*64 + c];
        else if (r < 128){
            int h = r - 64; float s = 0.f;
            for (int m = 0; m < 64; m++)
                s = fmaf(ws[WT2_OFF + h*64 + m], ws[CW_OFF + (64+m)*64 + c], s);
            v = s;
        } else if (r < 192){
            int h = r - 128; float s = 0.f;
            for (int m = 0; m < 64; m++)
                s = fmaf(ws[WF2_OFF + h*64 + m], ws[CW_OFF + (128+m)*64 + c], s);
            v = s;
        } else if (r < 194) v = ws[CW_OFF + r*64 + c];
        else if (r == 194){
            float s = 0.f;
            for (int m = 0; m < 64; m++)
                s = fmaf(ws[BT2_OFF + m], ws[CW_OFF + (64+m)*64 + c], s);
            v = s;
        } else {
            float s = 0.f;
            for (int m = 0; m < 64; m++)
                s = fmaf(ws[BF2_OFF + m], ws[CW_OFF + (128+m)*64 + c], s);
            v = s;
        }
        ws[NCW_OFF + j] = v;
    }
}

// ---- node setup ----
__global__ __launch_bounds__(256) void setup_node(const void* __restrict__ prb, float* __restrict__ ws){
    int i = blockIdx.x * 256 + threadIdx.x;
    if (i >= N) return;
    bool isbf = ws[FLAG_OFF] > 0.5f;
    ws[PRB0_OFF+i] = ldv(prb, 2*i,   isbf);
    ws[PRB1_OFF+i] = ldv(prb, 2*i+1, isbf);
    if (i < NBUK){
        int* wsI = (int*)ws;
        wsI[BKC_OFF+i] = 0; wsI[BKR_OFF+i] = 0;
    }
}

// ---- bucket histogram ----
__global__ __launch_bounds__(256) void bucket_hist(const int* __restrict__ ei, int* __restrict__ wsI){
    __shared__ int hc[NBUK], hr[NBUK];
    int t = threadIdx.x;
    for (int i = t; i < NBUK; i += 256){ hc[i] = 0; hr[i] = 0; }
    __syncthreads();
    int e0 = blockIdx.x * 4096;
    for (int i = 0; i < 16; i++){
        int e = e0 + i*256 + t;
        if (e < E){
            int r = ei[e], c = ei[E+e];
            if (r != c) atomicAdd(&hc[c >> 8], 1);
            atomicAdd(&hr[r >> 8], 1);
        }
    }
    __syncthreads();
    if (t < NBUK){
        if (hc[t]) atomicAdd(&wsI[BKC_OFF+t], hc[t]);
        if (hr[t]) atomicAdd(&wsI[BKR_OFF+t], hr[t]);
    }
}

// ---- bucket scan ----
__global__ __launch_bounds__(256) void bucket_scan(int* __restrict__ wsI){
    int y = blockIdx.y, t = threadIdx.x;
    const int* bk = wsI + (y ? BKR_OFF : BKC_OFF);
    int* gb = wsI + (y ? GBR_OFF : GBC_OFF);
    int* gf = wsI + (y ? GFR_OFF : GFC_OFF);
    __shared__ int sh[256];
    int v = (t < NBUK) ? bk[t] : 0;
    sh[t] = v;
    __syncthreads();
    #pragma unroll
    for (int off = 1; off < 256; off <<= 1){
        int u = (t >= (unsigned)off) ? sh[t - off] : 0;
        __syncthreads();
        sh[t] += u;
        __syncthreads();
    }
    int base = sh[t] - v;
    if (t < NBUK){ gb[t] = base; gf[t] = base; }
    if (t == NBUK - 1) gb[NBUK] = sh[t];
}

// ---- binned scatter phase A ----
__global__ __launch_bounds__(256) void scatter_binA(const int* __restrict__ ei,
                                                    const void* __restrict__ attr,
                                                    const void* __restrict__ aij,
                                                    float* __restrict__ ws){
    __shared__ int hc[NBUK], hr[NBUK], bc[NBUK], br[NBUK];
    int t = threadIdx.x;
    for (int i = t; i < NBUK; i += 256){ hc[i] = 0; hr[i] = 0; }
    __syncthreads();
    int* wsI = (int*)ws;
    int e0 = blockIdx.x * 4096;
    for (int i = 0; i < 16; i++){
        int e = e0 + i*256 + t;
        if (e < E){
            int r = ei[e], c = ei[E+e];
            if (r != c) atomicAdd(&hc[c >> 8], 1);
            atomicAdd(&hr[r >> 8], 1);
        }
    }
    __syncthreads();
    if (t < NBUK){
        bc[t] = atomicAdd(&wsI[GFC_OFF+t], hc[t]);
        br[t] = atomicAdd(&wsI[GFR_OFF+t], hr[t]);
        hc[t] = 0; hr[t] = 0;
    }
    __syncthreads();
    bool isbf = ws[FLAG_OFF] > 0.5f;
    uint4* cstg = (uint4*)(ws + CSTG_OFF);
    uint4* rstg = (uint4*)(ws + RSTG_OFF);
    for (int i = 0; i < 16; i++){
        int e = e0 + i*256 + t;
        if (e < E){
            int r = ei[e], c = ei[E+e];
            unsigned a0 = ld16(attr, 3*e, isbf), a1 = ld16(attr, 3*e+1, isbf);
            unsigned a2 = ld16(attr, 3*e+2, isbf), av = ld16(aij, e, isbf);
            unsigned a01 = a0 | (a1 << 16);
            if (r != c){
                int off = atomicAdd(&hc[c >> 8], 1);
                cstg[bc[c >> 8] + off] = make_uint4((unsigned)r | (a2 << 16), a01, (unsigned)c, 0u);
            }
            int off2 = atomicAdd(&hr[r >> 8], 1);
            rstg[br[r >> 8] + off2] = make_uint4((unsigned)c | (a2 << 16), a01, av << 16, (unsigned)r);
        }
    }
}

// ---- per-bucket degree count ----
__global__ __launch_bounds__(256) void deg_count(float* __restrict__ ws){
    __shared__ int cnt[256];
    __shared__ int scnt[256];
    int* wsI = (int*)ws;
    int b = blockIdx.x, t = threadIdx.x;
    cnt[t] = 0; scnt[t] = 0;
    __syncthreads();
    if (blockIdx.y == 0){
        int beg = wsI[GBC_OFF + b], end = wsI[GFC_OFF + b];
        const uint4* cstg = (const uint4*)(ws + CSTG_OFF);
        for (int p = beg + t; p < end; p += 256)
            atomicAdd(&cnt[(int)(cstg[p].z & 255u)], 1);
        __syncthreads();
        int node = b*256 + t;
        if (node < N) wsI[CDEG_OFF + node] = cnt[t];
    } else {
        int beg = wsI[GBR_OFF + b], end = wsI[GFR_OFF + b];
        const uint4* rstg = (const uint4*)(ws + RSTG_OFF);
        for (int p = beg + t; p < end; p += 256){
            uint4 q = rstg[p];
            int idx = (int)(q.w & 255u);
            atomicAdd(&cnt[idx], 1);
            if ((q.x & 0xffffu) == q.w) atomicAdd(&scnt[idx], 1);
        }
        __syncthreads();
        int node = b*256 + t;
        if (node < N){
            wsI[RDEG_OFF + node] = cnt[t];
            wsI[SDEG_OFF + node] = scnt[t];
        }
    }
}

DEV int deg_at(const int* wsI, int y, int i){
    if (y == 0) return wsI[CDEG_OFF+i];
    return wsI[RDEG_OFF+i];
}
__global__ __launch_bounds__(256) void scan1(int* __restrict__ wsI){
    int y = blockIdx.y;
    int* tmp = wsI + (y == 0 ? LCP_OFF : FRP_OFF);
    int i = blockIdx.x * 256 + threadIdx.x;
    __shared__ int sh[256];
    int v = (i < N) ? deg_at(wsI, y, i) : 0;
    sh[threadIdx.x] = v;
    __syncthreads();
    #pragma unroll
    for (int off = 1; off < 256; off <<= 1){
        int t = (threadIdx.x >= (unsigned)off) ? sh[threadIdx.x - off] : 0;
        __syncthreads();
        sh[threadIdx.x] += t;
        __syncthreads();
    }
    if (i < N) tmp[i] = sh[threadIdx.x] - v;
    if (threadIdx.x == 255) wsI[BS_OFF + y*256 + blockIdx.x] = sh[255];
}
__global__ __launch_bounds__(256) void scan2(int* __restrict__ wsI){
    int y = blockIdx.y, t = threadIdx.x;
    __shared__ int sh[256];
    int v = (t < 196) ? wsI[BS_OFF + y*256 + t] : 0;
    sh[t] = v;
    __syncthreads();
    #pragma unroll
    for (int off = 1; off < 256; off <<= 1){
        int u = (t >= (unsigned)off) ? sh[t - off] : 0;
        __syncthreads();
        sh[t] += u;
        __syncthreads();
    }
    wsI[BO_OFF + y*256 + t] = sh[t] - v;
}
__global__ __launch_bounds__(256) void scan3(int* __restrict__ wsI){
    int y = blockIdx.y;
    int* ptr = wsI + (y == 0 ? LCP_OFF : FRP_OFF);
    int i = blockIdx.x * 256 + threadIdx.x;
    if (i < N){
        int d = deg_at(wsI, y, i);
        int p = ptr[i] + wsI[BO_OFF + y*256 + blockIdx.x];
        ptr[i] = p;
        if (y == 0){
            wsI[LCF_OFF+i] = p;
            if (i == N-1) ptr[N] = p + d;
        } else {
            int live = wsI[RDEG_OFF+i] - wsI[SDEG_OFF+i];
            wsI[LRF_OFF+i] = p;
            wsI[LE_OFF+i]  = p + live;
            wsI[SFF_OFF+i] = p + live;
            if (i == N-1) ptr[N] = E;
        }
    }
}

// ---- binned scatter phase B ----
__global__ __launch_bounds__(256) void scatter_binB(float* __restrict__ ws){
    int* wsI = (int*)ws;
    int b = blockIdx.x;
    if (blockIdx.y == 0){
        int beg = wsI[GBC_OFF + b];
        int end = wsI[GFC_OFF + b];
        const uint4* cstg = (const uint4*)(ws + CSTG_OFF);
        uint2* crec = (uint2*)(ws + CREC_OFF);
        for (int p = beg + threadIdx.x; p < end; p += 256){
            uint4 q = cstg[p];
            int d = atomicAdd(&wsI[LCF_OFF + (int)q.z], 1);
            crec[d] = make_uint2(q.x, q.y);
        }
    } else {
        int beg = wsI[GBR_OFF + b];
        int end = wsI[GFR_OFF + b];
        const uint4* rstg = (const uint4*)(ws + RSTG_OFF);
        uint4* rrec = (uint4*)(ws + RREC_OFF);
        for (int p = beg + threadIdx.x; p < end; p += 256){
            uint4 q = rstg[p];
            int r = (int)q.w;
            int c = (int)(q.x & 0xffffu);
            int d = (r != c) ? atomicAdd(&wsI[LRF_OFF + r], 1)
                             : atomicAdd(&wsI[SFF_OFF + r], 1);
            rrec[d] = make_uint4(q.x, q.y, q.z, 0u);
        }
    }
}

// ---- encoder ----
__global__ __launch_bounds__(256) void encode_init(const void* __restrict__ x,
                                                   float* __restrict__ ws){
    int node = blockIdx.x * 256 + threadIdx.x;
    if (node >= N) return;
    bool isbf = ws[FLAG_OFF] > 0.5f;
    int j0 = blockIdx.y * 32;
    float xv = ldv(x, node, isbf);
    float acc[32];
    #pragma unroll
    for (int j = 0; j < 32; j++) acc[j] = ws[EB2_OFF + j0 + j];
    for (int k = 0; k < 64; k++){
        float t = fmaxf(fmaf(xv, ws[EW1_OFF+k], ws[EB1_OFF+k]), 0.f);
        const float* wr = ws + EW2_OFF + (size_t)k*64 + j0;
        #pragma unroll
        for (int j = 0; j < 32; j++) acc[j] = fmaf(t, wr[j], acc[j]);
    }
    unsigned short* hb = (unsigned short*)(ws + HB_OFF);
    #pragma unroll
    for (int j = 0; j < 32; j++){
        ws[H0F_OFF + (size_t)(j0+j)*N + node] = acc[j];
        ws[HF_OFF  + (size_t)(j0+j)*N + node] = acc[j];
        hb[(size_t)(j0+j)*N + node] = f2b(acc[j]);
    }
}

// ---- first-layer precompute (r13 form: global weights) ----
__global__ __launch_bounds__(256) void node_pre(float* __restrict__ ws){
    int node = blockIdx.x * 256 + threadIdx.x;
    if (node >= N) return;
    int dir = blockIdx.y >> 1, tl = blockIdx.y & 1;
    int j0 = tl * 32;
    const float* W1 = ws + (dir ? PF1_OFF : PT1_OFF);
    float* paOut = ws + (dir ? PAF_OFF : PAT_OFF);
    unsigned short* pbOut = (unsigned short*)(ws + (dir ? PBF_OFF : PBT_OFF));
    const unsigned short* hb = (const unsigned short*)(ws + HB_OFF);
    float aA[32], aB[32];
    #pragma unroll
    for (int j = 0; j < 32; j++){ aA[j] = 0.f; aB[j] = 0.f; }
    #pragma unroll 4
    for (int k = 0; k < 64; k++){
        float hv = b2f(hb[(size_t)k*N + node]);
        const float* wA = W1 + (size_t)k*64 + j0;
        const float* wB = W1 + (size_t)(64+k)*64 + j0;
        #pragma unroll
        for (int j = 0; j < 32; j++){
            aA[j] = fmaf(hv, wA[j], aA[j]);
            aB[j] = fmaf(hv, wB[j], aB[j]);
        }
    }
    #pragma unroll
    for (int j = 0; j < 32; j++){
        paOut[(size_t)node*64 + j0 + j] = aA[j];
        pbOut[(size_t)node*64 + j0 + j] = f2b(aB[j]);
    }
}

// ---- CSR message gather ----
template<int DIR>
__global__ __launch_bounds__(256) void gather_msgs(float* __restrict__ ws){
    const int* wsI = (const int*)ws;
    float* pa = ws + (DIR ? PAF_OFF : PAT_OFF);
    const unsigned short* pgb = (const unsigned short*)(ws + (DIR ? PBF_OFF : PBT_OFF));
    const float* A3 = ws + (DIR ? AF_OFF : AT_OFF);
    const float* b1 = ws + (DIR ? BF1_OFF : BT1_OFF);

    int lane = threadIdx.x & 63;
    int wv = threadIdx.x >> 6;
    float A0 = A3[lane], A1 = A3[64+lane], A2 = A3[128+lane];
    float B1 = b1[lane];
    int gw = blockIdx.x * 4 + wv;
    int nw = gridDim.x * 4;
    for (int node = gw; node < N; node += nw){
        float pav = pa[(size_t)node*64 + lane] + B1;
        float hs = 0.f;
        int beg, end;
        if (DIR == 0){ beg = wsI[LCP_OFF+node]; end = wsI[LCP_OFF+node+1]; }
        else         { beg = wsI[FRP_OFF+node]; end = wsI[LE_OFF+node]; }
        int cnt = end - beg;
        for (int base = beg; base < end; base += 64){
            int mcnt = end - base; if (mcnt > 64) mcnt = 64;
            unsigned rxL = 0, ryL = 0;
            if (lane < mcnt){
                if (DIR == 0){
                    uint2 q = ((const uint2*)(ws + CREC_OFF))[base + lane];
                    rxL = q.x; ryL = q.y;
                } else {
                    uint4 q = ((const uint4*)(ws + RREC_OFF))[base + lane];
                    rxL = q.x; ryL = q.y;
                }
            }
            for (int g = 0; g < mcnt; g += 8){
                unsigned rxa[8], rya[8];
                float pb[8];
                #pragma unroll
                for (int t = 0; t < 8; t++){
                    rxa[t] = (unsigned)bcasti((int)rxL, g+t);
                    rya[t] = (unsigned)bcasti((int)ryL, g+t);
                    int o = (int)(rxa[t] & 0xffffu);
                    float pv = b2f(pgb[(size_t)o*64 + lane]);
                    pb[t] = (g+t < mcnt) ? pv : -3.0e38f;
                }
                #pragma unroll
                for (int t = 0; t < 8; t++){
                    float hv = fmaf(blo(rya[t]), A0,
                               fmaf(bhi(rya[t]), A1,
                               fmaf(bhi(rxa[t]), A2, pav))) + pb[t];
                    hs += fmaxf(hv, 0.f);
                }
            }
        }
        pa[(size_t)node*64 + lane] = hs;
        if (lane == 0) ws[CNT_OFF + DIR*N + node] = (float)cnt;
    }
}

// ---- fused transpose: PAT+PAF [node][64] f32 -> MP uint[64][N] (mt | mf<<16) ----
__global__ __launch_bounds__(256) void transpose_msg(float* __restrict__ ws){
    __shared__ float t[64][65];
    __shared__ float u[64][65];
    const float* srcT = ws + PAT_OFF;
    const float* srcF = ws + PAF_OFF;
    unsigned* mp = (unsigned*)(ws + MP_OFF);
    int n0 = blockIdx.x * 64;
    #pragma unroll
    for (int i = 0; i < 16; i++){
        int idx = i*256 + threadIdx.x;
        int nl = idx >> 6, f = idx & 63;
        int node = n0 + nl;
        t[nl][f] = (node < N) ? srcT[(size_t)node*64 + f] : 0.f;
        u[nl][f] = (node < N) ? srcF[(size_t)node*64 + f] : 0.f;
    }
    __syncthreads();
    #pragma unroll
    for (int i = 0; i < 16; i++){
        int idx = i*256 + threadIdx.x;
        int fw = idx >> 6, nl = idx & 63;
        int node = n0 + nl;
        if (node < N)
            mp[(size_t)fw*N + node] = (unsigned)f2b(t[nl][fw]) | ((unsigned)f2b(u[nl][fw]) << 16);
    }
}

// ---- gate z+r: j-tile 16, packed mt|mf stream, global weights (r13 form) ----
__global__ __launch_bounds__(256) void gate_zr(float* __restrict__ ws){
    int node = blockIdx.x * 256 + threadIdx.x;
    if (node >= N) return;
    int tl = blockIdx.y, j0 = tl * 16;
    const float* W = ws + NWZR_OFF + j0;
    const unsigned short* hb = (const unsigned short*)(ws + HB_OFF);
    const unsigned* mp = (const unsigned*)(ws + MP_OFF);
    float p0 = ws[PRB0_OFF+node], p1 = ws[PRB1_OFF+node];
    float cT = ws[CNT_OFF+node], cF = ws[CNT_OFF+N+node];
    float az[16], ar[16];
    #pragma unroll
    for (int j = 0; j < 16; j++){
        az[j] = ws[GB_OFF + j0 + j]
              + p0*W[192*128+j] + p1*W[193*128+j] + cT*W[194*128+j] + cF*W[195*128+j];
        ar[j] = ws[GB_OFF + 64 + j0 + j]
              + p0*W[192*128+64+j] + p1*W[193*128+64+j] + cT*W[194*128+64+j] + cF*W[195*128+64+j];
    }
    #pragma unroll 4
    for (int k = 0; k < 64; k++){
        float aH = b2f(hb[(size_t)k*N + node]);
        unsigned m = mp[(size_t)k*N + node];
        float aT = blo(m), aF = bhi(m);
        const float* wH = W + (size_t)k*128;
        const float* wT = W + (size_t)(64+k)*128;
        const float* wF = W + (size_t)(128+k)*128;
        #pragma unroll
        for (int j = 0; j < 16; j++){
            az[j] = fmaf(aH, wH[j], fmaf(aT, wT[j], fmaf(aF, wF[j], az[j])));
            ar[j] = fmaf(aH, wH[64+j], fmaf(aT, wT[64+j], fmaf(aF, wF[64+j], ar[j])));
        }
    }
    unsigned short* RH = (unsigned short*)(ws + RH_OFF);
    #pragma unroll
    for (int j = 0; j < 16; j++){
        size_t off = (size_t)(j0+j)*N + node;
        ws[AL_OFF + off] = sigm(az[j]);
        RH[off] = f2b(sigm(ar[j]) * b2f(hb[off]));
    }
}

// ---- gate corr + update: j-tile 16, packed stream, global weights ----
__global__ __launch_bounds__(256) void gate_corr(const int* __restrict__ tags,
                                                 float* __restrict__ ws){
    int node = blockIdx.x * 256 + threadIdx.x;
    if (node >= N) return;
    int tl = blockIdx.y, j0 = tl*16;
    const float* W = ws + NCW_OFF + j0;
    const unsigned short* RH = (const unsigned short*)(ws + RH_OFF);
    const unsigned* mp = (const unsigned*)(ws + MP_OFF);
    float p0 = ws[PRB0_OFF+node], p1 = ws[PRB1_OFF+node];
    float cT = ws[CNT_OFF+node], cF = ws[CNT_OFF+N+node];
    float acc[16];
    #pragma unroll
    for (int j = 0; j < 16; j++)
        acc[j] = ws[CB_OFF + j0 + j]
               + p0*W[192*64+j] + p1*W[193*64+j] + cT*W[194*64+j] + cF*W[195*64+j];
    #pragma unroll 4
    for (int k = 0; k < 64; k++){
        float aR = b2f(RH[(size_t)k*N + node]);
        unsigned m = mp[(size_t)k*N + node];
        float aT = blo(m), aF = bhi(m);
        const float* wR = W + (size_t)k*64;
        const float* wT = W + (size_t)(64+k)*64;
        const float* wF = W + (size_t)(128+k)*64;
        #pragma unroll
        for (int j = 0; j < 16; j++)
            acc[j] = fmaf(aR, wR[j], fmaf(aT, wT[j], fmaf(aF, wF[j], acc[j])));
    }
    int tg = tags[node];
    unsigned short* hb = (unsigned short*)(ws + HB_OFF);
    #pragma unroll
    for (int j = 0; j < 16; j++){
        size_t off = (size_t)(j0+j)*N + node;
        float hn = fmaf(ws[AL_OFF+off], tanhf(acc[j]), ws[HF_OFF+off]);
        if (tg == 1) hn = ws[H0F_OFF+off];
        ws[HF_OFF+off] = hn;
        hb[off] = f2b(hn);
    }
}

// ---- decode stage 1, bf16 src -> f32 dst (r13 form) ----
__global__ __launch_bounds__(256) void dec1hf(const unsigned short* __restrict__ src,
                                              float* __restrict__ dst,
                                              float* __restrict__ ws){
    int node = blockIdx.x * 256 + threadIdx.x;
    if (node >= N) return;
    int j0 = blockIdx.y * 32;
    float acc[32];
    #pragma unroll
    for (int j = 0; j < 32; j++) acc[j] = ws[DB1_OFF + j0 + j];
    #pragma unroll 4
    for (int k = 0; k < 64; k++){
        float a = b2f(src[(size_t)k*N + node]);
        const float* wr = ws + DW1_OFF + (size_t)k*64 + j0;
        #pragma unroll
        for (int j = 0; j < 32; j++) acc[j] = fmaf(a, wr[j], acc[j]);
    }
    #pragma unroll
    for (int j = 0; j < 32; j++)
        dst[(size_t)(j0+j)*N + node] = fmaxf(acc[j], 0.f);
}

// ---- decode stage 1, bf16 src -> bf16 dst (r13 form) ----
__global__ __launch_bounds__(256) void dec1hb(const unsigned short* __restrict__ src,
                                              unsigned short* __restrict__ dst,
                                              float* __restrict__ ws){
    int node = blockIdx.x * 256 + threadIdx.x;
    if (node >= N) return;
    int j0 = blockIdx.y * 32;
    float acc[32];
    #pragma unroll
    for (int j = 0; j < 32; j++) acc[j] = ws[DB1_OFF + j0 + j];
    #pragma unroll 4
    for (int k = 0; k < 64; k++){
        float a = b2f(src[(size_t)k*N + node]);
        const float* wr = ws + DW1_OFF + (size_t)k*64 + j0;
        #pragma unroll
        for (int j = 0; j < 32; j++) acc[j] = fmaf(a, wr[j], acc[j]);
    }
    #pragma unroll
    for (int j = 0; j < 32; j++)
        dst[(size_t)(j0+j)*N + node] = f2b(fmaxf(acc[j], 0.f));
}

// ---- decode stage 2 + encode(u) + enc loss; EV bf16 (r13 form) ----
__global__ __launch_bounds__(256) void enc_u(int step, float* __restrict__ ws){
    int node = blockIdx.x * 256 + threadIdx.x;
    float encA = 0.f;
    if (node < N){
        int j0 = blockIdx.y * 32;
        float u = ws[DB2_OFF];
        for (int j = 0; j < 64; j++)
            u = fmaf(ws[T1_OFF + (size_t)j*N + node], ws[DW2_OFF+j], u);
        if (blockIdx.y == 0) ws[UV_OFF+node] = u;
        float acc[32];
        #pragma unroll
        for (int j = 0; j < 32; j++) acc[j] = ws[EB2_OFF + j0 + j];
        for (int k = 0; k < 64; k++){
            float t = fmaxf(fmaf(u, ws[EW1_OFF+k], ws[EB1_OFF+k]), 0.f);
            const float* wr = ws + EW2_OFF + (size_t)k*64 + j0;
            #pragma unroll
            for (int j = 0; j < 32; j++) acc[j] = fmaf(t, wr[j], acc[j]);
        }
        unsigned short* ev = (unsigned short*)(ws + EV_OFF);
        #pragma unroll
        for (int j = 0; j < 32; j++){
            size_t off = (size_t)(j0+j)*N + node;
            ev[off] = f2b(acc[j]);
            float d = acc[j] - ws[HF_OFF+off];
            encA += d*d;
        }
    }
    encA = wave_sum(encA);
    if ((threadIdx.x & 63) == 0) atomicAdd(&ws[LOSS_OFF + step*3 + 1], encA);
}

// ---- final: u2 = dec(E) (bf16 T1), auto loss, residual, res loss (r13 form) ----
__global__ __launch_bounds__(256) void aux_res(int step, const void* __restrict__ y,
                                               float* __restrict__ ws){
    const int* wsI = (const int*)ws;
    int node = blockIdx.x * 256 + threadIdx.x;
    bool isbf = ws[FLAG_OFF] > 0.5f;
    float autoA = 0.f, resA = 0.f;
    if (node < N){
        const unsigned short* T1u = (const unsigned short*)(ws + T1_OFF);
        float u2 = ws[DB2_OFF];
        for (int j = 0; j < 64; j++)
            u2 = fmaf(b2f(T1u[(size_t)j*N + node]), ws[DW2_OFF+j], u2);
        float u = ws[UV_OFF+node];
        float ad = u2 - u;
        autoA = ad*ad;
        float acc = 0.f;
        int beg = wsI[FRP_OFF+node], end = wsI[FRP_OFF+node+1];
        const uint4* rrec = (const uint4*)(ws + RREC_OFF);
        for (int p = beg; p < end; p++){
            uint4 q = rrec[p];
            acc = fmaf(bhi(q.z), ws[UV_OFF + (int)(q.x & 0xffffu)], acc);
        }
        float d = acc - ldv(y, node, isbf);
        resA = d*d;
    }
    autoA = wave_sum(autoA);
    resA = wave_sum(resA);
    if ((threadIdx.x & 63) == 0){
        atomicAdd(&ws[LOSS_OFF + step*3 + 2], autoA);
        atomicAdd(&ws[LOSS_OFF + step*3], resA);
    }
}

// ---- output writer ----
__global__ __launch_bounds__(256) void write_out(void* __restrict__ outp,
                                                 const float* __restrict__ ws){
    int i = blockIdx.x * 256 + threadIdx.x;
    if (i > N) return;
    bool isbf = ws[FLAG_OFF] > 0.5f;
    float v;
    if (i < N){
        v = ws[UV_OFF+i];
    } else {
        const float* L = ws + LOSS_OFF;
        float inv = 1.f / (float)N, invl = 1.f / ((float)N * 64.f);
        v = 0.9f*L[0]*inv + L[1]*invl + L[2]*inv
          +      L[3]*inv + L[4]*invl + L[5]*inv;
    }
    if (isbf) ((unsigned short*)outp)[i] = f2b(v);
    else      ((float*)outp)[i] = v;
}

extern "C" void kernel_launch(void* const* d_in, const int* in_sizes, int n_in,
                              void* d_out, int out_size, void* d_ws, size_t ws_size,
                              hipStream_t stream){
    const void* x    = d_in[0];
    const void* y    = d_in[2];
    const int* tags  = (const int*)d_in[3];
    const int* ei    = (const int*)d_in[4];
    const void* attr = d_in[5];
    const void* aij  = d_in[6];
    const void* prb  = d_in[7];
    WPtrs P;
    P.ptW1 = d_in[8];  P.ptb1 = d_in[9];  P.ptW2 = d_in[10]; P.ptb2 = d_in[11];
    P.pfW1 = d_in[12]; P.pfb1 = d_in[13]; P.pfW2 = d_in[14]; P.pfb2 = d_in[15];
    P.zkW  = d_in[16]; P.zkb  = d_in[17]; P.rkW  = d_in[18]; P.rkb  = d_in[19];
    P.cW   = d_in[20]; P.cb   = d_in[21];
    P.eW1  = d_in[22]; P.eb1  = d_in[23]; P.eW2  = d_in[24]; P.eb2  = d_in[25];
    P.dW1  = d_in[26]; P.db1  = d_in[27]; P.dW2  = d_in[28]; P.db2  = d_in[29];
    float* ws = (float*)d_ws;
    int* wsI = (int*)d_ws;

    detect_kernel<<<1, 256, 0, stream>>>(y, ws);
    prep_kernel<<<(PREP_TOTAL + 255)/256, 256, 0, stream>>>(P, ws);
    prep2_kernel<<<(PREP2_TOTAL + 255)/256, 256, 0, stream>>>(ws);
    setup_node<<<196, 256, 0, stream>>>(prb, ws);
    bucket_hist<<<196, 256, 0, stream>>>(ei, wsI);
    bucket_scan<<<dim3(1, 2), 256, 0, stream>>>(wsI);
    scatter_binA<<<196, 256, 0, stream>>>(ei, attr, aij, ws);
    deg_count<<<dim3(196, 2), 256, 0, stream>>>(ws);
    scan1<<<dim3(196, 2), 256, 0, stream>>>(wsI);
    scan2<<<dim3(1, 2), 256, 0, stream>>>(wsI);
    scan3<<<dim3(196, 2), 256, 0, stream>>>(wsI);
    scatter_binB<<<dim3(196, 2), 256, 0, stream>>>(ws);
    encode_init<<<dim3(196, 2), 256, 0, stream>>>(x, ws);
    unsigned short* hb = (unsigned short*)(ws + HB_OFF);
    unsigned short* ev = (unsigned short*)(ws + EV_OFF);
    for (int step = 0; step < 2; step++){
        node_pre<<<dim3(196, 4), 256, 0, stream>>>(ws);
        gather_msgs<0><<<2048, 256, 0, stream>>>(ws);
        gather_msgs<1><<<2048, 256, 0, stream>>>(ws);
        transpose_msg<<<782, 256, 0, stream>>>(ws);
        gate_zr<<<dim3(196, 4), 256, 0, stream>>>(ws);
        gate_corr<<<dim3(196, 4), 256, 0, stream>>>(tags, ws);
        dec1hf<<<dim3(196, 2), 256, 0, stream>>>(hb, ws + T1_OFF, ws);
        enc_u<<<dim3(196, 2), 256, 0, stream>>>(step, ws);
        dec1hb<<<dim3(196, 2), 256, 0, stream>>>(ev, (unsigned short*)(ws + T1_OFF), ws);
        aux_res<<<196, 256, 0, stream>>>(step, y, ws);
    }
    write_out<<<197, 256, 0, stream>>>(d_out, ws);
}

// Round 17
// 869.417 us; speedup vs baseline: 1.0953x; 1.0635x over previous
//
#include <hip/hip_runtime.h>

#define DEV __device__ __forceinline__

constexpr int N = 50000;
constexpr int E = 800000;
constexpr int NBUK = 196;

// ---- float region (4-byte units) ----
constexpr int HF_OFF  = 0;
constexpr int H0F_OFF = 64*N;
constexpr int MTF_OFF = 128*N;              // packed mt|mf uint [64][N] after transpose (aliased PBT/PBF before)
constexpr int MFF_OFF = 160*N;
constexpr int PBT_OFF = MTF_OFF;
constexpr int PBF_OFF = MFF_OFF;
constexpr int MP_OFF  = MTF_OFF;            // uint[64][N]
constexpr int R1_OFF  = 192*N;
constexpr int PAT_OFF = R1_OFF;
constexpr int PAF_OFF = R1_OFF + 64*N;
constexpr int AL_OFF  = R1_OFF;
constexpr int RH_OFF  = R1_OFF + 64*N;
constexpr int T1_OFF  = R1_OFF;
constexpr int EV_OFF  = R1_OFF + 64*N;
constexpr int CSTG_OFF = R1_OFF;
constexpr int RSTG_OFF = R1_OFF + 4*E;
constexpr int HB_OFF   = 352*N;
constexpr int UV_OFF   = 384*N;
constexpr int LOSS_OFF = UV_OFF + N;
constexpr int FLAG_OFF = LOSS_OFF + 7;
constexpr int WZR_OFF = LOSS_OFF + 8;
constexpr int GB_OFF  = WZR_OFF + 24832;
constexpr int CW_OFF  = GB_OFF + 128;
constexpr int CB_OFF  = CW_OFF + 12416;
constexpr int PT1_OFF = CB_OFF + 64;
constexpr int AT_OFF  = PT1_OFF + 8192;
constexpr int BT1_OFF = AT_OFF + 192;
constexpr int WT2_OFF = BT1_OFF + 64;
constexpr int BT2_OFF = WT2_OFF + 4096;
constexpr int PF1_OFF = BT2_OFF + 64;
constexpr int AF_OFF  = PF1_OFF + 8192;
constexpr int BF1_OFF = AF_OFF + 192;
constexpr int WF2_OFF = BF1_OFF + 64;
constexpr int BF2_OFF = WF2_OFF + 4096;
constexpr int DW1_OFF = BF2_OFF + 64;
constexpr int DW2_OFF = DW1_OFF + 4096;
constexpr int DB1_OFF = DW2_OFF + 64;
constexpr int DB2_OFF = DB1_OFF + 64;
constexpr int EW1_OFF = DB2_OFF + 4;
constexpr int EB1_OFF = EW1_OFF + 64;
constexpr int EW2_OFF = EB1_OFF + 64;
constexpr int EB2_OFF = EW2_OFF + 4096;
constexpr int PRB0_OFF = EB2_OFF + 64;
constexpr int PRB1_OFF = PRB0_OFF + N;
constexpr int NWZR_OFF = PRB1_OFF + N;      // 196*128
constexpr int NCW_OFF  = NWZR_OFF + 25088;  // 196*64
constexpr int CNT_OFF  = NCW_OFF + 12544;   // 2N
constexpr int FEND     = CNT_OFF + 2*N;
constexpr int CREC_OFF = FEND;
constexpr int RREC_OFF = CREC_OFF + 2*E;
constexpr int LCP_OFF  = RREC_OFF + 4*E;
constexpr int FRP_OFF  = LCP_OFF + N + 1;
constexpr int LE_OFF   = FRP_OFF + N + 1;
constexpr int LCF_OFF  = LE_OFF + N;
constexpr int LRF_OFF  = LCF_OFF + N;
constexpr int SFF_OFF  = LRF_OFF + N;
constexpr int CDEG_OFF = SFF_OFF + N;
constexpr int RDEG_OFF = CDEG_OFF + N;
constexpr int SDEG_OFF = RDEG_OFF + N;
constexpr int BS_OFF   = SDEG_OFF + N;
constexpr int BO_OFF   = BS_OFF + 512;
constexpr int GFC_OFF  = BO_OFF + 512;
constexpr int GFR_OFF  = GFC_OFF + 196;
constexpr int BKC_OFF  = GFR_OFF + 196;
constexpr int BKR_OFF  = BKC_OFF + 196;
constexpr int GBC_OFF  = BKR_OFF + 196;
constexpr int GBR_OFF  = GBC_OFF + 197;

constexpr int PREP_TOTAL = 24832+128+12416+64+8192+192+64+4096+64+8192+192+64+4096+64+4096+64+64+1+64+64+4096+64+6;
constexpr int PREP2_TOTAL = 25088 + 12544;

DEV float b2f(unsigned short u){ return __uint_as_float(((unsigned)u) << 16); }
DEV unsigned short f2b(float f){
    unsigned u = __float_as_uint(f);
    return (unsigned short)((u + 0x7fffu + ((u >> 16) & 1u)) >> 16);
}
DEV float blo(unsigned u){ return __uint_as_float(u << 16); }
DEV float bhi(unsigned u){ return __uint_as_float(u & 0xffff0000u); }
DEV int bcasti(int v, int k){ return __builtin_amdgcn_readlane(v, k); }
DEV float wave_sum(float v){
    #pragma unroll
    for (int off = 32; off > 0; off >>= 1) v += __shfl_xor(v, off, 64);
    return v;
}
DEV float ldv(const void* p, int i, bool isbf){
    return isbf ? b2f(((const unsigned short*)p)[i]) : ((const float*)p)[i];
}
DEV unsigned short ld16(const void* p, int i, bool isbf){
    return isbf ? ((const unsigned short*)p)[i] : f2b(((const float*)p)[i]);
}
DEV float sigm(float x){ return 1.f / (1.f + __expf(-x)); }

struct WPtrs {
    const void *ptW1, *ptb1, *ptW2, *ptb2;
    const void *pfW1, *pfb1, *pfW2, *pfb2;
    const void *zkW, *zkb, *rkW, *rkb, *cW, *cb;
    const void *eW1, *eb1, *eW2, *eb2;
    const void *dW1, *db1, *dW2, *db2;
};

// ---- dtype detection ----
__global__ __launch_bounds__(256) void detect_kernel(const void* y, float* __restrict__ ws){
    __shared__ int bad;
    if (threadIdx.x == 0) bad = 0;
    __syncthreads();
    const unsigned short* yy = (const unsigned short*)y;
    int mybad = 0;
    for (int i = threadIdx.x; i < 4096; i += 256){
        float v = b2f(yy[i]);
        if (!(v > -1.0e6f && v < 1.0e6f)) mybad = 1;
    }
    if (mybad) bad = 1;
    __syncthreads();
    if (threadIdx.x == 0) ws[FLAG_OFF] = bad ? 0.0f : 1.0f;
}

// ---- weight prep (pass 1) ----
__global__ __launch_bounds__(256) void prep_kernel(WPtrs P, float* __restrict__ ws){
    int j = blockIdx.x * 256 + threadIdx.x;
    if (j >= PREP_TOTAL) return;
    bool isbf = ws[FLAG_OFF] > 0.5f;
    if (j < 24832){
        int k = j >> 7, c = j & 127;
        ws[WZR_OFF+j] = (c < 64) ? ldv(P.zkW, k*64+c, isbf) : ldv(P.rkW, k*64+(c-64), isbf);
        return;
    } j -= 24832;
    if (j < 128){ ws[GB_OFF+j] = (j < 64) ? ldv(P.zkb, j, isbf) : ldv(P.rkb, j-64, isbf); return; } j -= 128;
    if (j < 12416){ ws[CW_OFF+j] = ldv(P.cW, j, isbf); return; } j -= 12416;
    if (j < 64){ ws[CB_OFF+j] = ldv(P.cb, j, isbf); return; } j -= 64;
    if (j < 8192){ ws[PT1_OFF+j] = ldv(P.ptW1, j, isbf); return; } j -= 8192;
    if (j < 192){ ws[AT_OFF+j] = ldv(P.ptW1, 128*64+j, isbf); return; } j -= 192;
    if (j < 64){ ws[BT1_OFF+j] = ldv(P.ptb1, j, isbf); return; } j -= 64;
    if (j < 4096){ ws[WT2_OFF+j] = ldv(P.ptW2, j, isbf); return; } j -= 4096;
    if (j < 64){ ws[BT2_OFF+j] = ldv(P.ptb2, j, isbf); return; } j -= 64;
    if (j < 8192){ ws[PF1_OFF+j] = ldv(P.pfW1, j, isbf); return; } j -= 8192;
    if (j < 192){ ws[AF_OFF+j] = ldv(P.pfW1, 128*64+j, isbf); return; } j -= 192;
    if (j < 64){ ws[BF1_OFF+j] = ldv(P.pfb1, j, isbf); return; } j -= 64;
    if (j < 4096){ ws[WF2_OFF+j] = ldv(P.pfW2, j, isbf); return; } j -= 4096;
    if (j < 64){ ws[BF2_OFF+j] = ldv(P.pfb2, j, isbf); return; } j -= 64;
    if (j < 4096){ ws[DW1_OFF+j] = ldv(P.dW1, j, isbf); return; } j -= 4096;
    if (j < 64){ ws[DW2_OFF+j] = ldv(P.dW2, j, isbf); return; } j -= 64;
    if (j < 64){ ws[DB1_OFF+j] = ldv(P.db1, j, isbf); return; } j -= 64;
    if (j < 1){ ws[DB2_OFF] = ldv(P.db2, 0, isbf); return; } j -= 1;
    if (j < 64){ ws[EW1_OFF+j] = ldv(P.eW1, j, isbf); return; } j -= 64;
    if (j < 64){ ws[EB1_OFF+j] = ldv(P.eb1, j, isbf); return; } j -= 64;
    if (j < 4096){ ws[EW2_OFF+j] = ldv(P.eW2, j, isbf); return; } j -= 4096;
    if (j < 64){ ws[EB2_OFF+j] = ldv(P.eb2, j, isbf); return; } j -= 64;
    ws[LOSS_OFF+j] = 0.f;
}

// ---- prep pass 2 ----
__global__ __launch_bounds__(256) void prep2_kernel(float* __restrict__ ws){
    int j = blockIdx.x * 256 + threadIdx.x;
    if (j >= PREP2_TOTAL) return;
    if (j < 25088){
        int r = j >> 7, c = j & 127;
        float v;
        if (r < 64) v = ws[WZR_OFF + r*128 + c];
        else if (r < 128){
            int h = r - 64; float s = 0.f;
            for (int m = 0; m < 64; m++)
                s = fmaf(ws[WT2_OFF + h*64 + m], ws[WZR_OFF + (64+m)*128 + c], s);
            v = s;
        } else if (r < 192){
            int h = r - 128; float s = 0.f;
            for (int m = 0; m < 64; m++)
                s = fmaf(ws[WF2_OFF + h*64 + m], ws[WZR_OFF + (128+m)*128 + c], s);
            v = s;
        } else if (r < 194) v = ws[WZR_OFF + r*128 + c];
        else if (r == 194){
            float s = 0.f;
            for (int m = 0; m < 64; m++)
                s = fmaf(ws[BT2_OFF + m], ws[WZR_OFF + (64+m)*128 + c], s);
            v = s;
        } else {
            float s = 0.f;
            for (int m = 0; m < 64; m++)
                s = fmaf(ws[BF2_OFF + m], ws[WZR_OFF + (128+m)*128 + c], s);
            v = s;
        }
        ws[NWZR_OFF + j] = v;
        return;
    }
    j -= 25088;
    {
        int r = j >> 6, c = j & 63;
        float v;
        if (r < 64) v = ws[CW_OFF + r*64 + c];
        else if (r < 128){
            int h = r - 64; float s = 0.f;
            for (int m = 0; m < 64; m++)
                s = fmaf(ws[WT2_OFF + h*64 + m], ws[CW_OFF + (64+m)*64 + c], s);
            v = s;
        } else if (r < 192){
            int h = r - 128; float s = 0.f;
            for (int m = 0; m < 64; m++)
                s = fmaf(ws[WF2_OFF + h*64 + m], ws[CW_OFF + (128+m)*64 + c], s);
            v = s;
        } else if (r < 194) v = ws[CW_OFF + r*64 + c];
        else if (r == 194){
            float s = 0.f;
            for (int m = 0; m < 64; m++)
                s = fmaf(ws[BT2_OFF + m], ws[CW_OFF + (64+m)*64 + c], s);
            v = s;
        } else {
            float s = 0.f;
            for (int m = 0; m < 64; m++)
                s = fmaf(ws[BF2_OFF + m], ws[CW_OFF + (128+m)*64 + c], s);
            v = s;
        }
        ws[NCW_OFF + j] = v;
    }
}

// ---- node setup ----
__global__ __launch_bounds__(256) void setup_node(const void* __restrict__ prb, float* __restrict__ ws){
    int i = blockIdx.x * 256 + threadIdx.x;
    if (i >= N) return;
    bool isbf = ws[FLAG_OFF] > 0.5f;
    ws[PRB0_OFF+i] = ldv(prb, 2*i,   isbf);
    ws[PRB1_OFF+i] = ldv(prb, 2*i+1, isbf);
    if (i < NBUK){
        int* wsI = (int*)ws;
        wsI[BKC_OFF+i] = 0; wsI[BKR_OFF+i] = 0;
    }
}

// ---- bucket histogram ----
__global__ __launch_bounds__(256) void bucket_hist(const int* __restrict__ ei, int* __restrict__ wsI){
    __shared__ int hc[NBUK], hr[NBUK];
    int t = threadIdx.x;
    for (int i = t; i < NBUK; i += 256){ hc[i] = 0; hr[i] = 0; }
    __syncthreads();
    int e0 = blockIdx.x * 4096;
    for (int i = 0; i < 16; i++){
        int e = e0 + i*256 + t;
        if (e < E){
            int r = ei[e], c = ei[E+e];
            if (r != c) atomicAdd(&hc[c >> 8], 1);
            atomicAdd(&hr[r >> 8], 1);
        }
    }
    __syncthreads();
    if (t < NBUK){
        if (hc[t]) atomicAdd(&wsI[BKC_OFF+t], hc[t]);
        if (hr[t]) atomicAdd(&wsI[BKR_OFF+t], hr[t]);
    }
}

// ---- bucket scan ----
__global__ __launch_bounds__(256) void bucket_scan(int* __restrict__ wsI){
    int y = blockIdx.y, t = threadIdx.x;
    const int* bk = wsI + (y ? BKR_OFF : BKC_OFF);
    int* gb = wsI + (y ? GBR_OFF : GBC_OFF);
    int* gf = wsI + (y ? GFR_OFF : GFC_OFF);
    __shared__ int sh[256];
    int v = (t < NBUK) ? bk[t] : 0;
    sh[t] = v;
    __syncthreads();
    #pragma unroll
    for (int off = 1; off < 256; off <<= 1){
        int u = (t >= (unsigned)off) ? sh[t - off] : 0;
        __syncthreads();
        sh[t] += u;
        __syncthreads();
    }
    int base = sh[t] - v;
    if (t < NBUK){ gb[t] = base; gf[t] = base; }
    if (t == NBUK - 1) gb[NBUK] = sh[t];
}

// ---- binned scatter phase A ----
__global__ __launch_bounds__(256) void scatter_binA(const int* __restrict__ ei,
                                                    const void* __restrict__ attr,
                                                    const void* __restrict__ aij,
                                                    float* __restrict__ ws){
    __shared__ int hc[NBUK], hr[NBUK], bc[NBUK], br[NBUK];
    int t = threadIdx.x;
    for (int i = t; i < NBUK; i += 256){ hc[i] = 0; hr[i] = 0; }
    __syncthreads();
    int* wsI = (int*)ws;
    int e0 = blockIdx.x * 4096;
    for (int i = 0; i < 16; i++){
        int e = e0 + i*256 + t;
        if (e < E){
            int r = ei[e], c = ei[E+e];
            if (r != c) atomicAdd(&hc[c >> 8], 1);
            atomicAdd(&hr[r >> 8], 1);
        }
    }
    __syncthreads();
    if (t < NBUK){
        bc[t] = atomicAdd(&wsI[GFC_OFF+t], hc[t]);
        br[t] = atomicAdd(&wsI[GFR_OFF+t], hr[t]);
        hc[t] = 0; hr[t] = 0;
    }
    __syncthreads();
    bool isbf = ws[FLAG_OFF] > 0.5f;
    uint4* cstg = (uint4*)(ws + CSTG_OFF);
    uint4* rstg = (uint4*)(ws + RSTG_OFF);
    for (int i = 0; i < 16; i++){
        int e = e0 + i*256 + t;
        if (e < E){
            int r = ei[e], c = ei[E+e];
            unsigned a0 = ld16(attr, 3*e, isbf), a1 = ld16(attr, 3*e+1, isbf);
            unsigned a2 = ld16(attr, 3*e+2, isbf), av = ld16(aij, e, isbf);
            unsigned a01 = a0 | (a1 << 16);
            if (r != c){
                int off = atomicAdd(&hc[c >> 8], 1);
                cstg[bc[c >> 8] + off] = make_uint4((unsigned)r | (a2 << 16), a01, (unsigned)c, 0u);
            }
            int off2 = atomicAdd(&hr[r >> 8], 1);
            rstg[br[r >> 8] + off2] = make_uint4((unsigned)c | (a2 << 16), a01, av << 16, (unsigned)r);
        }
    }
}

// ---- per-bucket degree count ----
__global__ __launch_bounds__(256) void deg_count(float* __restrict__ ws){
    __shared__ int cnt[256];
    __shared__ int scnt[256];
    int* wsI = (int*)ws;
    int b = blockIdx.x, t = threadIdx.x;
    cnt[t] = 0; scnt[t] = 0;
    __syncthreads();
    if (blockIdx.y == 0){
        int beg = wsI[GBC_OFF + b], end = wsI[GFC_OFF + b];
        const uint4* cstg = (const uint4*)(ws + CSTG_OFF);
        for (int p = beg + t; p < end; p += 256)
            atomicAdd(&cnt[(int)(cstg[p].z & 255u)], 1);
        __syncthreads();
        int node = b*256 + t;
        if (node < N) wsI[CDEG_OFF + node] = cnt[t];
    } else {
        int beg = wsI[GBR_OFF + b], end = wsI[GFR_OFF + b];
        const uint4* rstg = (const uint4*)(ws + RSTG_OFF);
        for (int p = beg + t; p < end; p += 256){
            uint4 q = rstg[p];
            int idx = (int)(q.w & 255u);
            atomicAdd(&cnt[idx], 1);
            if ((q.x & 0xffffu) == q.w) atomicAdd(&scnt[idx], 1);
        }
        __syncthreads();
        int node = b*256 + t;
        if (node < N){
            wsI[RDEG_OFF + node] = cnt[t];
            wsI[SDEG_OFF + node] = scnt[t];
        }
    }
}

DEV int deg_at(const int* wsI, int y, int i){
    if (y == 0) return wsI[CDEG_OFF+i];
    return wsI[RDEG_OFF+i];
}
__global__ __launch_bounds__(256) void scan1(int* __restrict__ wsI){
    int y = blockIdx.y;
    int* tmp = wsI + (y == 0 ? LCP_OFF : FRP_OFF);
    int i = blockIdx.x * 256 + threadIdx.x;
    __shared__ int sh[256];
    int v = (i < N) ? deg_at(wsI, y, i) : 0;
    sh[threadIdx.x] = v;
    __syncthreads();
    #pragma unroll
    for (int off = 1; off < 256; off <<= 1){
        int t = (threadIdx.x >= (unsigned)off) ? sh[threadIdx.x - off] : 0;
        __syncthreads();
        sh[threadIdx.x] += t;
        __syncthreads();
    }
    if (i < N) tmp[i] = sh[threadIdx.x] - v;
    if (threadIdx.x == 255) wsI[BS_OFF + y*256 + blockIdx.x] = sh[255];
}
__global__ __launch_bounds__(256) void scan2(int* __restrict__ wsI){
    int y = blockIdx.y, t = threadIdx.x;
    __shared__ int sh[256];
    int v = (t < 196) ? wsI[BS_OFF + y*256 + t] : 0;
    sh[t] = v;
    __syncthreads();
    #pragma unroll
    for (int off = 1; off < 256; off <<= 1){
        int u = (t >= (unsigned)off) ? sh[t - off] : 0;
        __syncthreads();
        sh[t] += u;
        __syncthreads();
    }
    wsI[BO_OFF + y*256 + t] = sh[t] - v;
}
__global__ __launch_bounds__(256) void scan3(int* __restrict__ wsI){
    int y = blockIdx.y;
    int* ptr = wsI + (y == 0 ? LCP_OFF : FRP_OFF);
    int i = blockIdx.x * 256 + threadIdx.x;
    if (i < N){
        int d = deg_at(wsI, y, i);
        int p = ptr[i] + wsI[BO_OFF + y*256 + blockIdx.x];
        ptr[i] = p;
        if (y == 0){
            wsI[LCF_OFF+i] = p;
            if (i == N-1) ptr[N] = p + d;
        } else {
            int live = wsI[RDEG_OFF+i] - wsI[SDEG_OFF+i];
            wsI[LRF_OFF+i] = p;
            wsI[LE_OFF+i]  = p + live;
            wsI[SFF_OFF+i] = p + live;
            if (i == N-1) ptr[N] = E;
        }
    }
}

// ---- binned scatter phase B ----
__global__ __launch_bounds__(256) void scatter_binB(float* __restrict__ ws){
    int* wsI = (int*)ws;
    int b = blockIdx.x;
    if (blockIdx.y == 0){
        int beg = wsI[GBC_OFF + b];
        int end = wsI[GFC_OFF + b];
        const uint4* cstg = (const uint4*)(ws + CSTG_OFF);
        uint2* crec = (uint2*)(ws + CREC_OFF);
        for (int p = beg + threadIdx.x; p < end; p += 256){
            uint4 q = cstg[p];
            int d = atomicAdd(&wsI[LCF_OFF + (int)q.z], 1);
            crec[d] = make_uint2(q.x, q.y);
        }
    } else {
        int beg = wsI[GBR_OFF + b];
        int end = wsI[GFR_OFF + b];
        const uint4* rstg = (const uint4*)(ws + RSTG_OFF);
        uint4* rrec = (uint4*)(ws + RREC_OFF);
        for (int p = beg + threadIdx.x; p < end; p += 256){
            uint4 q = rstg[p];
            int r = (int)q.w;
            int c = (int)(q.x & 0xffffu);
            int d = (r != c) ? atomicAdd(&wsI[LRF_OFF + r], 1)
                             : atomicAdd(&wsI[SFF_OFF + r], 1);
            rrec[d] = make_uint4(q.x, q.y, q.z, 0u);
        }
    }
}

// ---- encoder ----
__global__ __launch_bounds__(256) void encode_init(const void* __restrict__ x,
                                                   float* __restrict__ ws){
    int node = blockIdx.x * 256 + threadIdx.x;
    if (node >= N) return;
    bool isbf = ws[FLAG_OFF] > 0.5f;
    int j0 = blockIdx.y * 32;
    float xv = ldv(x, node, isbf);
    float acc[32];
    #pragma unroll
    for (int j = 0; j < 32; j++) acc[j] = ws[EB2_OFF + j0 + j];
    for (int k = 0; k < 64; k++){
        float t = fmaxf(fmaf(xv, ws[EW1_OFF+k], ws[EB1_OFF+k]), 0.f);
        const float* wr = ws + EW2_OFF + (size_t)k*64 + j0;
        #pragma unroll
        for (int j = 0; j < 32; j++) acc[j] = fmaf(t, wr[j], acc[j]);
    }
    unsigned short* hb = (unsigned short*)(ws + HB_OFF);
    #pragma unroll
    for (int j = 0; j < 32; j++){
        ws[H0F_OFF + (size_t)(j0+j)*N + node] = acc[j];
        ws[HF_OFF  + (size_t)(j0+j)*N + node] = acc[j];
        hb[(size_t)(j0+j)*N + node] = f2b(acc[j]);
    }
}

// ---- first-layer precompute: j-tile 16, grid 196x8 ----
__global__ __launch_bounds__(256) void node_pre(float* __restrict__ ws){
    int node = blockIdx.x * 256 + threadIdx.x;
    if (node >= N) return;
    int dir = blockIdx.y >> 2, tl = blockIdx.y & 3;
    int j0 = tl * 16;
    const float* W1 = ws + (dir ? PF1_OFF : PT1_OFF);
    float* paOut = ws + (dir ? PAF_OFF : PAT_OFF);
    unsigned short* pbOut = (unsigned short*)(ws + (dir ? PBF_OFF : PBT_OFF));
    const unsigned short* hb = (const unsigned short*)(ws + HB_OFF);
    float aA[16], aB[16];
    #pragma unroll
    for (int j = 0; j < 16; j++){ aA[j] = 0.f; aB[j] = 0.f; }
    #pragma unroll 4
    for (int k = 0; k < 64; k++){
        float hv = b2f(hb[(size_t)k*N + node]);
        const float* wA = W1 + (size_t)k*64 + j0;
        const float* wB = W1 + (size_t)(64+k)*64 + j0;
        #pragma unroll
        for (int j = 0; j < 16; j++){
            aA[j] = fmaf(hv, wA[j], aA[j]);
            aB[j] = fmaf(hv, wB[j], aB[j]);
        }
    }
    #pragma unroll
    for (int j = 0; j < 16; j++){
        paOut[(size_t)node*64 + j0 + j] = aA[j];
        pbOut[(size_t)node*64 + j0 + j] = f2b(aB[j]);
    }
}

// ---- CSR message gather ----
template<int DIR>
__global__ __launch_bounds__(256) void gather_msgs(float* __restrict__ ws){
    const int* wsI = (const int*)ws;
    float* pa = ws + (DIR ? PAF_OFF : PAT_OFF);
    const unsigned short* pgb = (const unsigned short*)(ws + (DIR ? PBF_OFF : PBT_OFF));
    const float* A3 = ws + (DIR ? AF_OFF : AT_OFF);
    const float* b1 = ws + (DIR ? BF1_OFF : BT1_OFF);

    int lane = threadIdx.x & 63;
    int wv = threadIdx.x >> 6;
    float A0 = A3[lane], A1 = A3[64+lane], A2 = A3[128+lane];
    float B1 = b1[lane];
    int gw = blockIdx.x * 4 + wv;
    int nw = gridDim.x * 4;
    for (int node = gw; node < N; node += nw){
        float pav = pa[(size_t)node*64 + lane] + B1;
        float hs = 0.f;
        int beg, end;
        if (DIR == 0){ beg = wsI[LCP_OFF+node]; end = wsI[LCP_OFF+node+1]; }
        else         { beg = wsI[FRP_OFF+node]; end = wsI[LE_OFF+node]; }
        int cnt = end - beg;
        for (int base = beg; base < end; base += 64){
            int mcnt = end - base; if (mcnt > 64) mcnt = 64;
            unsigned rxL = 0, ryL = 0;
            if (lane < mcnt){
                if (DIR == 0){
                    uint2 q = ((const uint2*)(ws + CREC_OFF))[base + lane];
                    rxL = q.x; ryL = q.y;
                } else {
                    uint4 q = ((const uint4*)(ws + RREC_OFF))[base + lane];
                    rxL = q.x; ryL = q.y;
                }
            }
            for (int g = 0; g < mcnt; g += 8){
                unsigned rxa[8], rya[8];
                float pb[8];
                #pragma unroll
                for (int t = 0; t < 8; t++){
                    rxa[t] = (unsigned)bcasti((int)rxL, g+t);
                    rya[t] = (unsigned)bcasti((int)ryL, g+t);
                    int o = (int)(rxa[t] & 0xffffu);
                    float pv = b2f(pgb[(size_t)o*64 + lane]);
                    pb[t] = (g+t < mcnt) ? pv : -3.0e38f;
                }
                #pragma unroll
                for (int t = 0; t < 8; t++){
                    float hv = fmaf(blo(rya[t]), A0,
                               fmaf(bhi(rya[t]), A1,
                               fmaf(bhi(rxa[t]), A2, pav))) + pb[t];
                    hs += fmaxf(hv, 0.f);
                }
            }
        }
        pa[(size_t)node*64 + lane] = hs;
        if (lane == 0) ws[CNT_OFF + DIR*N + node] = (float)cnt;
    }
}

// ---- fused transpose: PAT+PAF [node][64] f32 -> MP uint[64][N] (mt | mf<<16) ----
__global__ __launch_bounds__(256) void transpose_msg(float* __restrict__ ws){
    __shared__ float t[64][65];
    __shared__ float u[64][65];
    const float* srcT = ws + PAT_OFF;
    const float* srcF = ws + PAF_OFF;
    unsigned* mp = (unsigned*)(ws + MP_OFF);
    int n0 = blockIdx.x * 64;
    #pragma unroll
    for (int i = 0; i < 16; i++){
        int idx = i*256 + threadIdx.x;
        int nl = idx >> 6, f = idx & 63;
        int node = n0 + nl;
        t[nl][f] = (node < N) ? srcT[(size_t)node*64 + f] : 0.f;
        u[nl][f] = (node < N) ? srcF[(size_t)node*64 + f] : 0.f;
    }
    __syncthreads();
    #pragma unroll
    for (int i = 0; i < 16; i++){
        int idx = i*256 + threadIdx.x;
        int fw = idx >> 6, nl = idx & 63;
        int node = n0 + nl;
        if (node < N)
            mp[(size_t)fw*N + node] = (unsigned)f2b(t[nl][fw]) | ((unsigned)f2b(u[nl][fw]) << 16);
    }
}

// ---- gate z+r: j-tile 8, grid 196x8, packed mt|mf stream ----
__global__ __launch_bounds__(256) void gate_zr(float* __restrict__ ws){
    int node = blockIdx.x * 256 + threadIdx.x;
    if (node >= N) return;
    int tl = blockIdx.y, j0 = tl * 8;
    const float* W = ws + NWZR_OFF + j0;
    const unsigned short* hb = (const unsigned short*)(ws + HB_OFF);
    const unsigned* mp = (const unsigned*)(ws + MP_OFF);
    float p0 = ws[PRB0_OFF+node], p1 = ws[PRB1_OFF+node];
    float cT = ws[CNT_OFF+node], cF = ws[CNT_OFF+N+node];
    float az[8], ar[8];
    #pragma unroll
    for (int j = 0; j < 8; j++){
        az[j] = ws[GB_OFF + j0 + j]
              + p0*W[192*128+j] + p1*W[193*128+j] + cT*W[194*128+j] + cF*W[195*128+j];
        ar[j] = ws[GB_OFF + 64 + j0 + j]
              + p0*W[192*128+64+j] + p1*W[193*128+64+j] + cT*W[194*128+64+j] + cF*W[195*128+64+j];
    }
    #pragma unroll 4
    for (int k = 0; k < 64; k++){
        float aH = b2f(hb[(size_t)k*N + node]);
        unsigned m = mp[(size_t)k*N + node];
        float aT = blo(m), aF = bhi(m);
        const float* wH = W + (size_t)k*128;
        const float* wT = W + (size_t)(64+k)*128;
        const float* wF = W + (size_t)(128+k)*128;
        #pragma unroll
        for (int j = 0; j < 8; j++){
            az[j] = fmaf(aH, wH[j], fmaf(aT, wT[j], fmaf(aF, wF[j], az[j])));
            ar[j] = fmaf(aH, wH[64+j], fmaf(aT, wT[64+j], fmaf(aF, wF[64+j], ar[j])));
        }
    }
    unsigned short* RH = (unsigned short*)(ws + RH_OFF);
    #pragma unroll
    for (int j = 0; j < 8; j++){
        size_t off = (size_t)(j0+j)*N + node;
        ws[AL_OFF + off] = sigm(az[j]);
        RH[off] = f2b(sigm(ar[j]) * b2f(hb[off]));
    }
}

// ---- gate corr + update: j-tile 8, grid 196x8 ----
__global__ __launch_bounds__(256) void gate_corr(const int* __restrict__ tags,
                                                 float* __restrict__ ws){
    int node = blockIdx.x * 256 + threadIdx.x;
    if (node >= N) return;
    int tl = blockIdx.y, j0 = tl*8;
    const float* W = ws + NCW_OFF + j0;
    const unsigned short* RH = (const unsigned short*)(ws + RH_OFF);
    const unsigned* mp = (const unsigned*)(ws + MP_OFF);
    float p0 = ws[PRB0_OFF+node], p1 = ws[PRB1_OFF+node];
    float cT = ws[CNT_OFF+node], cF = ws[CNT_OFF+N+node];
    float acc[8];
    #pragma unroll
    for (int j = 0; j < 8; j++)
        acc[j] = ws[CB_OFF + j0 + j]
               + p0*W[192*64+j] + p1*W[193*64+j] + cT*W[194*64+j] + cF*W[195*64+j];
    #pragma unroll 4
    for (int k = 0; k < 64; k++){
        float aR = b2f(RH[(size_t)k*N + node]);
        unsigned m = mp[(size_t)k*N + node];
        float aT = blo(m), aF = bhi(m);
        const float* wR = W + (size_t)k*64;
        const float* wT = W + (size_t)(64+k)*64;
        const float* wF = W + (size_t)(128+k)*64;
        #pragma unroll
        for (int j = 0; j < 8; j++)
            acc[j] = fmaf(aR, wR[j], fmaf(aT, wT[j], fmaf(aF, wF[j], acc[j])));
    }
    int tg = tags[node];
    unsigned short* hb = (unsigned short*)(ws + HB_OFF);
    #pragma unroll
    for (int j = 0; j < 8; j++){
        size_t off = (size_t)(j0+j)*N + node;
        float hn = fmaf(ws[AL_OFF+off], tanhf(acc[j]), ws[HF_OFF+off]);
        if (tg == 1) hn = ws[H0F_OFF+off];
        ws[HF_OFF+off] = hn;
        hb[off] = f2b(hn);
    }
}

// ---- decode stage 1: j-tile 16, grid 196x4, bf16 src -> f32 dst ----
__global__ __launch_bounds__(256) void dec1hf(const unsigned short* __restrict__ src,
                                              float* __restrict__ dst,
                                              float* __restrict__ ws){
    int node = blockIdx.x * 256 + threadIdx.x;
    if (node >= N) return;
    int j0 = blockIdx.y * 16;
    float acc[16];
    #pragma unroll
    for (int j = 0; j < 16; j++) acc[j] = ws[DB1_OFF + j0 + j];
    #pragma unroll 4
    for (int k = 0; k < 64; k++){
        float a = b2f(src[(size_t)k*N + node]);
        const float* wr = ws + DW1_OFF + (size_t)k*64 + j0;
        #pragma unroll
        for (int j = 0; j < 16; j++) acc[j] = fmaf(a, wr[j], acc[j]);
    }
    #pragma unroll
    for (int j = 0; j < 16; j++)
        dst[(size_t)(j0+j)*N + node] = fmaxf(acc[j], 0.f);
}

// ---- decode stage 1: j-tile 16, grid 196x4, bf16 src -> bf16 dst ----
__global__ __launch_bounds__(256) void dec1hb(const unsigned short* __restrict__ src,
                                              unsigned short* __restrict__ dst,
                                              float* __restrict__ ws){
    int node = blockIdx.x * 256 + threadIdx.x;
    if (node >= N) return;
    int j0 = blockIdx.y * 16;
    float acc[16];
    #pragma unroll
    for (int j = 0; j < 16; j++) acc[j] = ws[DB1_OFF + j0 + j];
    #pragma unroll 4
    for (int k = 0; k < 64; k++){
        float a = b2f(src[(size_t)k*N + node]);
        const float* wr = ws + DW1_OFF + (size_t)k*64 + j0;
        #pragma unroll
        for (int j = 0; j < 16; j++) acc[j] = fmaf(a, wr[j], acc[j]);
    }
    #pragma unroll
    for (int j = 0; j < 16; j++)
        dst[(size_t)(j0+j)*N + node] = f2b(fmaxf(acc[j], 0.f));
}

// ---- decode stage 2 + encode(u) + enc loss: j-tile 16, grid 196x4 ----
__global__ __launch_bounds__(256) void enc_u(int step, float* __restrict__ ws){
    int node = blockIdx.x * 256 + threadIdx.x;
    float encA = 0.f;
    if (node < N){
        int j0 = blockIdx.y * 16;
        float u = ws[DB2_OFF];
        for (int j = 0; j < 64; j++)
            u = fmaf(ws[T1_OFF + (size_t)j*N + node], ws[DW2_OFF+j], u);
        if (blockIdx.y == 0) ws[UV_OFF+node] = u;
        float acc[16];
        #pragma unroll
        for (int j = 0; j < 16; j++) acc[j] = ws[EB2_OFF + j0 + j];
        for (int k = 0; k < 64; k++){
            float t = fmaxf(fmaf(u, ws[EW1_OFF+k], ws[EB1_OFF+k]), 0.f);
            const float* wr = ws + EW2_OFF + (size_t)k*64 + j0;
            #pragma unroll
            for (int j = 0; j < 16; j++) acc[j] = fmaf(t, wr[j], acc[j]);
        }
        unsigned short* ev = (unsigned short*)(ws + EV_OFF);
        #pragma unroll
        for (int j = 0; j < 16; j++){
            size_t off = (size_t)(j0+j)*N + node;
            ev[off] = f2b(acc[j]);
            float d = acc[j] - ws[HF_OFF+off];
            encA += d*d;
        }
    }
    encA = wave_sum(encA);
    if ((threadIdx.x & 63) == 0) atomicAdd(&ws[LOSS_OFF + step*3 + 1], encA);
}

// ---- final: u2 = dec(E) (bf16 T1), auto loss, residual, res loss ----
__global__ __launch_bounds__(256) void aux_res(int step, const void* __restrict__ y,
                                               float* __restrict__ ws){
    const int* wsI = (const int*)ws;
    int node = blockIdx.x * 256 + threadIdx.x;
    bool isbf = ws[FLAG_OFF] > 0.5f;
    float autoA = 0.f, resA = 0.f;
    if (node < N){
        const unsigned short* T1u = (const unsigned short*)(ws + T1_OFF);
        float u2 = ws[DB2_OFF];
        for (int j = 0; j < 64; j++)
            u2 = fmaf(b2f(T1u[(size_t)j*N + node]), ws[DW2_OFF+j], u2);
        float u = ws[UV_OFF+node];
        float ad = u2 - u;
        autoA = ad*ad;
        float acc = 0.f;
        int beg = wsI[FRP_OFF+node], end = wsI[FRP_OFF+node+1];
        const uint4* rrec = (const uint4*)(ws + RREC_OFF);
        for (int p = beg; p < end; p++){
            uint4 q = rrec[p];
            acc = fmaf(bhi(q.z), ws[UV_OFF + (int)(q.x & 0xffffu)], acc);
        }
        float d = acc - ldv(y, node, isbf);
        resA = d*d;
    }
    autoA = wave_sum(autoA);
    resA = wave_sum(resA);
    if ((threadIdx.x & 63) == 0){
        atomicAdd(&ws[LOSS_OFF + step*3 + 2], autoA);
        atomicAdd(&ws[LOSS_OFF + step*3], resA);
    }
}

// ---- output writer ----
__global__ __launch_bounds__(256) void write_out(void* __restrict__ outp,
                                                 const float* __restrict__ ws){
    int i = blockIdx.x * 256 + threadIdx.x;
    if (i > N) return;
    bool isbf = ws[FLAG_OFF] > 0.5f;
    float v;
    if (i < N){
        v = ws[UV_OFF+i];
    } else {
        const float* L = ws + LOSS_OFF;
        float inv = 1.f / (float)N, invl = 1.f / ((float)N * 64.f);
        v = 0.9f*L[0]*inv + L[1]*invl + L[2]*inv
          +      L[3]*inv + L[4]*invl + L[5]*inv;
    }
    if (isbf) ((unsigned short*)outp)[i] = f2b(v);
    else      ((float*)outp)[i] = v;
}

extern "C" void kernel_launch(void* const* d_in, const int* in_sizes, int n_in,
                              void* d_out, int out_size, void* d_ws, size_t ws_size,
                              hipStream_t stream){
    const void* x    = d_in[0];
    const void* y    = d_in[2];
    const int* tags  = (const int*)d_in[3];
    const int* ei    = (const int*)d_in[4];
    const void* attr = d_in[5];
    const void* aij  = d_in[6];
    const void* prb  = d_in[7];
    WPtrs P;
    P.ptW1 = d_in[8];  P.ptb1 = d_in[9];  P.ptW2 = d_in[10]; P.ptb2 = d_in[11];
    P.pfW1 = d_in[12]; P.pfb1 = d_in[13]; P.pfW2 = d_in[14]; P.pfb2 = d_in[15];
    P.zkW  = d_in[16]; P.zkb  = d_in[17]; P.rkW  = d_in[18]; P.rkb  = d_in[19];
    P.cW   = d_in[20]; P.cb   = d_in[21];
    P.eW1  = d_in[22]; P.eb1  = d_in[23]; P.eW2  = d_in[24]; P.eb2  = d_in[25];
    P.dW1  = d_in[26]; P.db1  = d_in[27]; P.dW2  = d_in[28]; P.db2  = d_in[29];
    float* ws = (float*)d_ws;
    int* wsI = (int*)d_ws;

    detect_kernel<<<1, 256, 0, stream>>>(y, ws);
    prep_kernel<<<(PREP_TOTAL + 255)/256, 256, 0, stream>>>(P, ws);
    prep2_kernel<<<(PREP2_TOTAL + 255)/256, 256, 0, stream>>>(ws);
    setup_node<<<196, 256, 0, stream>>>(prb, ws);
    bucket_hist<<<196, 256, 0, stream>>>(ei, wsI);
    bucket_scan<<<dim3(1, 2), 256, 0, stream>>>(wsI);
    scatter_binA<<<196, 256, 0, stream>>>(ei, attr, aij, ws);
    deg_count<<<dim3(196, 2), 256, 0, stream>>>(ws);
    scan1<<<dim3(196, 2), 256, 0, stream>>>(wsI);
    scan2<<<dim3(1, 2), 256, 0, stream>>>(wsI);
    scan3<<<dim3(196, 2), 256, 0, stream>>>(wsI);
    scatter_binB<<<dim3(196, 2), 256, 0, stream>>>(ws);
    encode_init<<<dim3(196, 2), 256, 0, stream>>>(x, ws);
    unsigned short* hb = (unsigned short*)(ws + HB_OFF);
    unsigned short* ev = (unsigned short*)(ws + EV_OFF);
    for (int step = 0; step < 2; step++){
        node_pre<<<dim3(196, 8), 256, 0, stream>>>(ws);
        gather_msgs<0><<<2048, 256, 0, stream>>>(ws);
        gather_msgs<1><<<2048, 256, 0, stream>>>(ws);
        transpose_msg<<<782, 256, 0, stream>>>(ws);
        gate_zr<<<dim3(196, 8), 256, 0, stream>>>(ws);
        gate_corr<<<dim3(196, 8), 256, 0, stream>>>(tags, ws);
        dec1hf<<<dim3(196, 4), 256, 0, stream>>>(hb, ws + T1_OFF, ws);
        enc_u<<<dim3(196, 4), 256, 0, stream>>>(step, ws);
        dec1hb<<<dim3(196, 4), 256, 0, stream>>>(ev, (unsigned short*)(ws + T1_OFF), ws);
        aux_res<<<196, 256, 0, stream>>>(step, y, ws);
    }
    write_out<<<197, 256, 0, stream>>>(d_out, ws);
}

// Round 18
// 831.577 us; speedup vs baseline: 1.1451x; 1.0455x over previous
//
#include <hip/hip_runtime.h>

#define DEV __device__ __forceinline__

constexpr int N = 50000;
constexpr int E = 800000;
constexpr int NBUK = 196;

// ---- float region (4-byte units) ----
constexpr int HF_OFF  = 0;
constexpr int H0F_OFF = 64*N;
constexpr int MTF_OFF = 128*N;              // packed mt|mf uint [64][N] after transpose (aliased PBT/PBF before)
constexpr int MFF_OFF = 160*N;
constexpr int PBT_OFF = MTF_OFF;
constexpr int PBF_OFF = MFF_OFF;
constexpr int MP_OFF  = MTF_OFF;            // uint[64][N]
constexpr int R1_OFF  = 192*N;
constexpr int PAT_OFF = R1_OFF;
constexpr int PAF_OFF = R1_OFF + 64*N;
constexpr int AL_OFF  = R1_OFF;
constexpr int RH_OFF  = R1_OFF + 64*N;
constexpr int T1_OFF  = R1_OFF;
constexpr int EV_OFF  = R1_OFF + 64*N;
constexpr int CSTG_OFF = R1_OFF;
constexpr int RSTG_OFF = R1_OFF + 4*E;
constexpr int HB_OFF   = 352*N;
constexpr int UV_OFF   = 384*N;
constexpr int LOSS_OFF = UV_OFF + N;
constexpr int FLAG_OFF = LOSS_OFF + 7;
constexpr int WZR_OFF = LOSS_OFF + 8;
constexpr int GB_OFF  = WZR_OFF + 24832;
constexpr int CW_OFF  = GB_OFF + 128;
constexpr int CB_OFF  = CW_OFF + 12416;
constexpr int PT1_OFF = CB_OFF + 64;
constexpr int AT_OFF  = PT1_OFF + 8192;
constexpr int BT1_OFF = AT_OFF + 192;
constexpr int WT2_OFF = BT1_OFF + 64;
constexpr int BT2_OFF = WT2_OFF + 4096;
constexpr int PF1_OFF = BT2_OFF + 64;
constexpr int AF_OFF  = PF1_OFF + 8192;
constexpr int BF1_OFF = AF_OFF + 192;
constexpr int WF2_OFF = BF1_OFF + 64;
constexpr int BF2_OFF = WF2_OFF + 4096;
constexpr int DW1_OFF = BF2_OFF + 64;
constexpr int DW2_OFF = DW1_OFF + 4096;
constexpr int DB1_OFF = DW2_OFF + 64;
constexpr int DB2_OFF = DB1_OFF + 64;
constexpr int EW1_OFF = DB2_OFF + 4;
constexpr int EB1_OFF = EW1_OFF + 64;
constexpr int EW2_OFF = EB1_OFF + 64;
constexpr int EB2_OFF = EW2_OFF + 4096;
constexpr int PRB0_OFF = EB2_OFF + 64;
constexpr int PRB1_OFF = PRB0_OFF + N;
constexpr int NWZR_OFF = PRB1_OFF + N;      // 196*128
constexpr int NCW_OFF  = NWZR_OFF + 25088;  // 196*64
constexpr int CNT_OFF  = NCW_OFF + 12544;   // 2N
constexpr int FEND     = CNT_OFF + 2*N;
constexpr int CREC_OFF = FEND;
constexpr int RREC_OFF = CREC_OFF + 2*E;
constexpr int LCP_OFF  = RREC_OFF + 4*E;
constexpr int FRP_OFF  = LCP_OFF + N + 1;
constexpr int LE_OFF   = FRP_OFF + N + 1;
constexpr int LCF_OFF  = LE_OFF + N;
constexpr int LRF_OFF  = LCF_OFF + N;
constexpr int SFF_OFF  = LRF_OFF + N;
constexpr int CDEG_OFF = SFF_OFF + N;
constexpr int RDEG_OFF = CDEG_OFF + N;
constexpr int SDEG_OFF = RDEG_OFF + N;
constexpr int BS_OFF   = SDEG_OFF + N;
constexpr int BO_OFF   = BS_OFF + 512;
constexpr int GFC_OFF  = BO_OFF + 512;
constexpr int GFR_OFF  = GFC_OFF + 196;
constexpr int BKC_OFF  = GFR_OFF + 196;
constexpr int BKR_OFF  = BKC_OFF + 196;
constexpr int GBC_OFF  = BKR_OFF + 196;
constexpr int GBR_OFF  = GBC_OFF + 197;

constexpr int PREP_TOTAL = 24832+128+12416+64+8192+192+64+4096+64+8192+192+64+4096+64+4096+64+64+1+64+64+4096+64+6;
constexpr int PREP2_TOTAL = 25088 + 12544;

DEV float b2f(unsigned short u){ return __uint_as_float(((unsigned)u) << 16); }
DEV unsigned short f2b(float f){
    unsigned u = __float_as_uint(f);
    return (unsigned short)((u + 0x7fffu + ((u >> 16) & 1u)) >> 16);
}
DEV float blo(unsigned u){ return __uint_as_float(u << 16); }
DEV float bhi(unsigned u){ return __uint_as_float(u & 0xffff0000u); }
DEV int bcasti(int v, int k){ return __builtin_amdgcn_readlane(v, k); }
DEV float wave_sum(float v){
    #pragma unroll
    for (int off = 32; off > 0; off >>= 1) v += __shfl_xor(v, off, 64);
    return v;
}
DEV float ldv(const void* p, int i, bool isbf){
    return isbf ? b2f(((const unsigned short*)p)[i]) : ((const float*)p)[i];
}
DEV unsigned short ld16(const void* p, int i, bool isbf){
    return isbf ? ((const unsigned short*)p)[i] : f2b(((const float*)p)[i]);
}
DEV float sigm(float x){ return 1.f / (1.f + __expf(-x)); }

struct WPtrs {
    const void *ptW1, *ptb1, *ptW2, *ptb2;
    const void *pfW1, *pfb1, *pfW2, *pfb2;
    const void *zkW, *zkb, *rkW, *rkb, *cW, *cb;
    const void *eW1, *eb1, *eW2, *eb2;
    const void *dW1, *db1, *dW2, *db2;
};

// ---- dtype detection ----
__global__ __launch_bounds__(256) void detect_kernel(const void* y, float* __restrict__ ws){
    __shared__ int bad;
    if (threadIdx.x == 0) bad = 0;
    __syncthreads();
    const unsigned short* yy = (const unsigned short*)y;
    int mybad = 0;
    for (int i = threadIdx.x; i < 4096; i += 256){
        float v = b2f(yy[i]);
        if (!(v > -1.0e6f && v < 1.0e6f)) mybad = 1;
    }
    if (mybad) bad = 1;
    __syncthreads();
    if (threadIdx.x == 0) ws[FLAG_OFF] = bad ? 0.0f : 1.0f;
}

// ---- weight prep (pass 1) ----
__global__ __launch_bounds__(256) void prep_kernel(WPtrs P, float* __restrict__ ws){
    int j = blockIdx.x * 256 + threadIdx.x;
    if (j >= PREP_TOTAL) return;
    bool isbf = ws[FLAG_OFF] > 0.5f;
    if (j < 24832){
        int k = j >> 7, c = j & 127;
        ws[WZR_OFF+j] = (c < 64) ? ldv(P.zkW, k*64+c, isbf) : ldv(P.rkW, k*64+(c-64), isbf);
        return;
    } j -= 24832;
    if (j < 128){ ws[GB_OFF+j] = (j < 64) ? ldv(P.zkb, j, isbf) : ldv(P.rkb, j-64, isbf); return; } j -= 128;
    if (j < 12416){ ws[CW_OFF+j] = ldv(P.cW, j, isbf); return; } j -= 12416;
    if (j < 64){ ws[CB_OFF+j] = ldv(P.cb, j, isbf); return; } j -= 64;
    if (j < 8192){ ws[PT1_OFF+j] = ldv(P.ptW1, j, isbf); return; } j -= 8192;
    if (j < 192){ ws[AT_OFF+j] = ldv(P.ptW1, 128*64+j, isbf); return; } j -= 192;
    if (j < 64){ ws[BT1_OFF+j] = ldv(P.ptb1, j, isbf); return; } j -= 64;
    if (j < 4096){ ws[WT2_OFF+j] = ldv(P.ptW2, j, isbf); return; } j -= 4096;
    if (j < 64){ ws[BT2_OFF+j] = ldv(P.ptb2, j, isbf); return; } j -= 64;
    if (j < 8192){ ws[PF1_OFF+j] = ldv(P.pfW1, j, isbf); return; } j -= 8192;
    if (j < 192){ ws[AF_OFF+j] = ldv(P.pfW1, 128*64+j, isbf); return; } j -= 192;
    if (j < 64){ ws[BF1_OFF+j] = ldv(P.pfb1, j, isbf); return; } j -= 64;
    if (j < 4096){ ws[WF2_OFF+j] = ldv(P.pfW2, j, isbf); return; } j -= 4096;
    if (j < 64){ ws[BF2_OFF+j] = ldv(P.pfb2, j, isbf); return; } j -= 64;
    if (j < 4096){ ws[DW1_OFF+j] = ldv(P.dW1, j, isbf); return; } j -= 4096;
    if (j < 64){ ws[DW2_OFF+j] = ldv(P.dW2, j, isbf); return; } j -= 64;
    if (j < 64){ ws[DB1_OFF+j] = ldv(P.db1, j, isbf); return; } j -= 64;
    if (j < 1){ ws[DB2_OFF] = ldv(P.db2, 0, isbf); return; } j -= 1;
    if (j < 64){ ws[EW1_OFF+j] = ldv(P.eW1, j, isbf); return; } j -= 64;
    if (j < 64){ ws[EB1_OFF+j] = ldv(P.eb1, j, isbf); return; } j -= 64;
    if (j < 4096){ ws[EW2_OFF+j] = ldv(P.eW2, j, isbf); return; } j -= 4096;
    if (j < 64){ ws[EB2_OFF+j] = ldv(P.eb2, j, isbf); return; } j -= 64;
    ws[LOSS_OFF+j] = 0.f;
}

// ---- prep pass 2 ----
__global__ __launch_bounds__(256) void prep2_kernel(float* __restrict__ ws){
    int j = blockIdx.x * 256 + threadIdx.x;
    if (j >= PREP2_TOTAL) return;
    if (j < 25088){
        int r = j >> 7, c = j & 127;
        float v;
        if (r < 64) v = ws[WZR_OFF + r*128 + c];
        else if (r < 128){
            int h = r - 64; float s = 0.f;
            for (int m = 0; m < 64; m++)
                s = fmaf(ws[WT2_OFF + h*64 + m], ws[WZR_OFF + (64+m)*128 + c], s);
            v = s;
        } else if (r < 192){
            int h = r - 128; float s = 0.f;
            for (int m = 0; m < 64; m++)
                s = fmaf(ws[WF2_OFF + h*64 + m], ws[WZR_OFF + (128+m)*128 + c], s);
            v = s;
        } else if (r < 194) v = ws[WZR_OFF + r*128 + c];
        else if (r == 194){
            float s = 0.f;
            for (int m = 0; m < 64; m++)
                s = fmaf(ws[BT2_OFF + m], ws[WZR_OFF + (64+m)*128 + c], s);
            v = s;
        } else {
            float s = 0.f;
            for (int m = 0; m < 64; m++)
                s = fmaf(ws[BF2_OFF + m], ws[WZR_OFF + (128+m)*128 + c], s);
            v = s;
        }
        ws[NWZR_OFF + j] = v;
        return;
    }
    j -= 25088;
    {
        int r = j >> 6, c = j & 63;
        float v;
        if (r < 64) v = ws[CW_OFF + r*64 + c];
        else if (r < 128){
            int h = r - 64; float s = 0.f;
            for (int m = 0; m < 64; m++)
                s = fmaf(ws[WT2_OFF + h*64 + m], ws[CW_OFF + (64+m)*64 + c], s);
            v = s;
        } else if (r < 192){
            int h = r - 128; float s = 0.f;
            for (int m = 0; m < 64; m++)
                s = fmaf(ws[WF2_OFF + h*64 + m], ws[CW_OFF + (128+m)*64 + c], s);
            v = s;
        } else if (r < 194) v = ws[CW_OFF + r*64 + c];
        else if (r == 194){
            float s = 0.f;
            for (int m = 0; m < 64; m++)
                s = fmaf(ws[BT2_OFF + m], ws[CW_OFF + (64+m)*64 + c], s);
            v = s;
        } else {
            float s = 0.f;
            for (int m = 0; m < 64; m++)
                s = fmaf(ws[BF2_OFF + m], ws[CW_OFF + (128+m)*64 + c], s);
            v = s;
        }
        ws[NCW_OFF + j] = v;
    }
}

// ---- node setup ----
__global__ __launch_bounds__(256) void setup_node(const void* __restrict__ prb, float* __restrict__ ws){
    int i = blockIdx.x * 256 + threadIdx.x;
    if (i >= N) return;
    bool isbf = ws[FLAG_OFF] > 0.5f;
    ws[PRB0_OFF+i] = ldv(prb, 2*i,   isbf);
    ws[PRB1_OFF+i] = ldv(prb, 2*i+1, isbf);
    if (i < NBUK){
        int* wsI = (int*)ws;
        wsI[BKC_OFF+i] = 0; wsI[BKR_OFF+i] = 0;
    }
}

// ---- bucket histogram ----
__global__ __launch_bounds__(256) void bucket_hist(const int* __restrict__ ei, int* __restrict__ wsI){
    __shared__ int hc[NBUK], hr[NBUK];
    int t = threadIdx.x;
    for (int i = t; i < NBUK; i += 256){ hc[i] = 0; hr[i] = 0; }
    __syncthreads();
    int e0 = blockIdx.x * 4096;
    for (int i = 0; i < 16; i++){
        int e = e0 + i*256 + t;
        if (e < E){
            int r = ei[e], c = ei[E+e];
            if (r != c) atomicAdd(&hc[c >> 8], 1);
            atomicAdd(&hr[r >> 8], 1);
        }
    }
    __syncthreads();
    if (t < NBUK){
        if (hc[t]) atomicAdd(&wsI[BKC_OFF+t], hc[t]);
        if (hr[t]) atomicAdd(&wsI[BKR_OFF+t], hr[t]);
    }
}

// ---- bucket scan ----
__global__ __launch_bounds__(256) void bucket_scan(int* __restrict__ wsI){
    int y = blockIdx.y, t = threadIdx.x;
    const int* bk = wsI + (y ? BKR_OFF : BKC_OFF);
    int* gb = wsI + (y ? GBR_OFF : GBC_OFF);
    int* gf = wsI + (y ? GFR_OFF : GFC_OFF);
    __shared__ int sh[256];
    int v = (t < NBUK) ? bk[t] : 0;
    sh[t] = v;
    __syncthreads();
    #pragma unroll
    for (int off = 1; off < 256; off <<= 1){
        int u = (t >= (unsigned)off) ? sh[t - off] : 0;
        __syncthreads();
        sh[t] += u;
        __syncthreads();
    }
    int base = sh[t] - v;
    if (t < NBUK){ gb[t] = base; gf[t] = base; }
    if (t == NBUK - 1) gb[NBUK] = sh[t];
}

// ---- binned scatter phase A ----
__global__ __launch_bounds__(256) void scatter_binA(const int* __restrict__ ei,
                                                    const void* __restrict__ attr,
                                                    const void* __restrict__ aij,
                                                    float* __restrict__ ws){
    __shared__ int hc[NBUK], hr[NBUK], bc[NBUK], br[NBUK];
    int t = threadIdx.x;
    for (int i = t; i < NBUK; i += 256){ hc[i] = 0; hr[i] = 0; }
    __syncthreads();
    int* wsI = (int*)ws;
    int e0 = blockIdx.x * 4096;
    for (int i = 0; i < 16; i++){
        int e = e0 + i*256 + t;
        if (e < E){
            int r = ei[e], c = ei[E+e];
            if (r != c) atomicAdd(&hc[c >> 8], 1);
            atomicAdd(&hr[r >> 8], 1);
        }
    }
    __syncthreads();
    if (t < NBUK){
        bc[t] = atomicAdd(&wsI[GFC_OFF+t], hc[t]);
        br[t] = atomicAdd(&wsI[GFR_OFF+t], hr[t]);
        hc[t] = 0; hr[t] = 0;
    }
    __syncthreads();
    bool isbf = ws[FLAG_OFF] > 0.5f;
    uint4* cstg = (uint4*)(ws + CSTG_OFF);
    uint4* rstg = (uint4*)(ws + RSTG_OFF);
    for (int i = 0; i < 16; i++){
        int e = e0 + i*256 + t;
        if (e < E){
            int r = ei[e], c = ei[E+e];
            unsigned a0 = ld16(attr, 3*e, isbf), a1 = ld16(attr, 3*e+1, isbf);
            unsigned a2 = ld16(attr, 3*e+2, isbf), av = ld16(aij, e, isbf);
            unsigned a01 = a0 | (a1 << 16);
            if (r != c){
                int off = atomicAdd(&hc[c >> 8], 1);
                cstg[bc[c >> 8] + off] = make_uint4((unsigned)r | (a2 << 16), a01, (unsigned)c, 0u);
            }
            int off2 = atomicAdd(&hr[r >> 8], 1);
            rstg[br[r >> 8] + off2] = make_uint4((unsigned)c | (a2 << 16), a01, av << 16, (unsigned)r);
        }
    }
}

// ---- per-bucket degree count ----
__global__ __launch_bounds__(256) void deg_count(float* __restrict__ ws){
    __shared__ int cnt[256];
    __shared__ int scnt[256];
    int* wsI = (int*)ws;
    int b = blockIdx.x, t = threadIdx.x;
    cnt[t] = 0; scnt[t] = 0;
    __syncthreads();
    if (blockIdx.y == 0){
        int beg = wsI[GBC_OFF + b], end = wsI[GFC_OFF + b];
        const uint4* cstg = (const uint4*)(ws + CSTG_OFF);
        for (int p = beg + t; p < end; p += 256)
            atomicAdd(&cnt[(int)(cstg[p].z & 255u)], 1);
        __syncthreads();
        int node = b*256 + t;
        if (node < N) wsI[CDEG_OFF + node] = cnt[t];
    } else {
        int beg = wsI[GBR_OFF + b], end = wsI[GFR_OFF + b];
        const uint4* rstg = (const uint4*)(ws + RSTG_OFF);
        for (int p = beg + t; p < end; p += 256){
            uint4 q = rstg[p];
            int idx = (int)(q.w & 255u);
            atomicAdd(&cnt[idx], 1);
            if ((q.x & 0xffffu) == q.w) atomicAdd(&scnt[idx], 1);
        }
        __syncthreads();
        int node = b*256 + t;
        if (node < N){
            wsI[RDEG_OFF + node] = cnt[t];
            wsI[SDEG_OFF + node] = scnt[t];
        }
    }
}

DEV int deg_at(const int* wsI, int y, int i){
    if (y == 0) return wsI[CDEG_OFF+i];
    return wsI[RDEG_OFF+i];
}
__global__ __launch_bounds__(256) void scan1(int* __restrict__ wsI){
    int y = blockIdx.y;
    int* tmp = wsI + (y == 0 ? LCP_OFF : FRP_OFF);
    int i = blockIdx.x * 256 + threadIdx.x;
    __shared__ int sh[256];
    int v = (i < N) ? deg_at(wsI, y, i) : 0;
    sh[threadIdx.x] = v;
    __syncthreads();
    #pragma unroll
    for (int off = 1; off < 256; off <<= 1){
        int t = (threadIdx.x >= (unsigned)off) ? sh[threadIdx.x - off] : 0;
        __syncthreads();
        sh[threadIdx.x] += t;
        __syncthreads();
    }
    if (i < N) tmp[i] = sh[threadIdx.x] - v;
    if (threadIdx.x == 255) wsI[BS_OFF + y*256 + blockIdx.x] = sh[255];
}
__global__ __launch_bounds__(256) void scan2(int* __restrict__ wsI){
    int y = blockIdx.y, t = threadIdx.x;
    __shared__ int sh[256];
    int v = (t < 196) ? wsI[BS_OFF + y*256 + t] : 0;
    sh[t] = v;
    __syncthreads();
    #pragma unroll
    for (int off = 1; off < 256; off <<= 1){
        int u = (t >= (unsigned)off) ? sh[t - off] : 0;
        __syncthreads();
        sh[t] += u;
        __syncthreads();
    }
    wsI[BO_OFF + y*256 + t] = sh[t] - v;
}
__global__ __launch_bounds__(256) void scan3(int* __restrict__ wsI){
    int y = blockIdx.y;
    int* ptr = wsI + (y == 0 ? LCP_OFF : FRP_OFF);
    int i = blockIdx.x * 256 + threadIdx.x;
    if (i < N){
        int d = deg_at(wsI, y, i);
        int p = ptr[i] + wsI[BO_OFF + y*256 + blockIdx.x];
        ptr[i] = p;
        if (y == 0){
            wsI[LCF_OFF+i] = p;
            if (i == N-1) ptr[N] = p + d;
        } else {
            int live = wsI[RDEG_OFF+i] - wsI[SDEG_OFF+i];
            wsI[LRF_OFF+i] = p;
            wsI[LE_OFF+i]  = p + live;
            wsI[SFF_OFF+i] = p + live;
            if (i == N-1) ptr[N] = E;
        }
    }
}

// ---- binned scatter phase B ----
__global__ __launch_bounds__(256) void scatter_binB(float* __restrict__ ws){
    int* wsI = (int*)ws;
    int b = blockIdx.x;
    if (blockIdx.y == 0){
        int beg = wsI[GBC_OFF + b];
        int end = wsI[GFC_OFF + b];
        const uint4* cstg = (const uint4*)(ws + CSTG_OFF);
        uint2* crec = (uint2*)(ws + CREC_OFF);
        for (int p = beg + threadIdx.x; p < end; p += 256){
            uint4 q = cstg[p];
            int d = atomicAdd(&wsI[LCF_OFF + (int)q.z], 1);
            crec[d] = make_uint2(q.x, q.y);
        }
    } else {
        int beg = wsI[GBR_OFF + b];
        int end = wsI[GFR_OFF + b];
        const uint4* rstg = (const uint4*)(ws + RSTG_OFF);
        uint4* rrec = (uint4*)(ws + RREC_OFF);
        for (int p = beg + threadIdx.x; p < end; p += 256){
            uint4 q = rstg[p];
            int r = (int)q.w;
            int c = (int)(q.x & 0xffffu);
            int d = (r != c) ? atomicAdd(&wsI[LRF_OFF + r], 1)
                             : atomicAdd(&wsI[SFF_OFF + r], 1);
            rrec[d] = make_uint4(q.x, q.y, q.z, 0u);
        }
    }
}

// ---- encoder ----
__global__ __launch_bounds__(256) void encode_init(const void* __restrict__ x,
                                                   float* __restrict__ ws){
    int node = blockIdx.x * 256 + threadIdx.x;
    if (node >= N) return;
    bool isbf = ws[FLAG_OFF] > 0.5f;
    int j0 = blockIdx.y * 32;
    float xv = ldv(x, node, isbf);
    float acc[32];
    #pragma unroll
    for (int j = 0; j < 32; j++) acc[j] = ws[EB2_OFF + j0 + j];
    for (int k = 0; k < 64; k++){
        float t = fmaxf(fmaf(xv, ws[EW1_OFF+k], ws[EB1_OFF+k]), 0.f);
        const float* wr = ws + EW2_OFF + (size_t)k*64 + j0;
        #pragma unroll
        for (int j = 0; j < 32; j++) acc[j] = fmaf(t, wr[j], acc[j]);
    }
    unsigned short* hb = (unsigned short*)(ws + HB_OFF);
    #pragma unroll
    for (int j = 0; j < 32; j++){
        ws[H0F_OFF + (size_t)(j0+j)*N + node] = acc[j];
        ws[HF_OFF  + (size_t)(j0+j)*N + node] = acc[j];
        hb[(size_t)(j0+j)*N + node] = f2b(acc[j]);
    }
}

// ---- first-layer precompute: j-tile 16, grid 196x8 ----
__global__ __launch_bounds__(256) void node_pre(float* __restrict__ ws){
    int node = blockIdx.x * 256 + threadIdx.x;
    if (node >= N) return;
    int dir = blockIdx.y >> 2, tl = blockIdx.y & 3;
    int j0 = tl * 16;
    const float* W1 = ws + (dir ? PF1_OFF : PT1_OFF);
    float* paOut = ws + (dir ? PAF_OFF : PAT_OFF);
    unsigned short* pbOut = (unsigned short*)(ws + (dir ? PBF_OFF : PBT_OFF));
    const unsigned short* hb = (const unsigned short*)(ws + HB_OFF);
    float aA[16], aB[16];
    #pragma unroll
    for (int j = 0; j < 16; j++){ aA[j] = 0.f; aB[j] = 0.f; }
    #pragma unroll 4
    for (int k = 0; k < 64; k++){
        float hv = b2f(hb[(size_t)k*N + node]);
        const float* wA = W1 + (size_t)k*64 + j0;
        const float* wB = W1 + (size_t)(64+k)*64 + j0;
        #pragma unroll
        for (int j = 0; j < 16; j++){
            aA[j] = fmaf(hv, wA[j], aA[j]);
            aB[j] = fmaf(hv, wB[j], aB[j]);
        }
    }
    #pragma unroll
    for (int j = 0; j < 16; j++){
        paOut[(size_t)node*64 + j0 + j] = aA[j];
        pbOut[(size_t)node*64 + j0 + j] = f2b(aB[j]);
    }
}

// ---- CSR message gather ----
template<int DIR>
__global__ __launch_bounds__(256) void gather_msgs(float* __restrict__ ws){
    const int* wsI = (const int*)ws;
    float* pa = ws + (DIR ? PAF_OFF : PAT_OFF);
    const unsigned short* pgb = (const unsigned short*)(ws + (DIR ? PBF_OFF : PBT_OFF));
    const float* A3 = ws + (DIR ? AF_OFF : AT_OFF);
    const float* b1 = ws + (DIR ? BF1_OFF : BT1_OFF);

    int lane = threadIdx.x & 63;
    int wv = threadIdx.x >> 6;
    float A0 = A3[lane], A1 = A3[64+lane], A2 = A3[128+lane];
    float B1 = b1[lane];
    int gw = blockIdx.x * 4 + wv;
    int nw = gridDim.x * 4;
    for (int node = gw; node < N; node += nw){
        float pav = pa[(size_t)node*64 + lane] + B1;
        float hs = 0.f;
        int beg, end;
        if (DIR == 0){ beg = wsI[LCP_OFF+node]; end = wsI[LCP_OFF+node+1]; }
        else         { beg = wsI[FRP_OFF+node]; end = wsI[LE_OFF+node]; }
        int cnt = end - beg;
        for (int base = beg; base < end; base += 64){
            int mcnt = end - base; if (mcnt > 64) mcnt = 64;
            unsigned rxL = 0, ryL = 0;
            if (lane < mcnt){
                if (DIR == 0){
                    uint2 q = ((const uint2*)(ws + CREC_OFF))[base + lane];
                    rxL = q.x; ryL = q.y;
                } else {
                    uint4 q = ((const uint4*)(ws + RREC_OFF))[base + lane];
                    rxL = q.x; ryL = q.y;
                }
            }
            for (int g = 0; g < mcnt; g += 8){
                unsigned rxa[8], rya[8];
                float pb[8];
                #pragma unroll
                for (int t = 0; t < 8; t++){
                    rxa[t] = (unsigned)bcasti((int)rxL, g+t);
                    rya[t] = (unsigned)bcasti((int)ryL, g+t);
                    int o = (int)(rxa[t] & 0xffffu);
                    float pv = b2f(pgb[(size_t)o*64 + lane]);
                    pb[t] = (g+t < mcnt) ? pv : -3.0e38f;
                }
                #pragma unroll
                for (int t = 0; t < 8; t++){
                    float hv = fmaf(blo(rya[t]), A0,
                               fmaf(bhi(rya[t]), A1,
                               fmaf(bhi(rxa[t]), A2, pav))) + pb[t];
                    hs += fmaxf(hv, 0.f);
                }
            }
        }
        pa[(size_t)node*64 + lane] = hs;
        if (lane == 0) ws[CNT_OFF + DIR*N + node] = (float)cnt;
    }
}

// ---- fused transpose: PAT+PAF [node][64] f32 -> MP uint[64][N] (mt | mf<<16) ----
__global__ __launch_bounds__(256) void transpose_msg(float* __restrict__ ws){
    __shared__ float t[64][65];
    __shared__ float u[64][65];
    const float* srcT = ws + PAT_OFF;
    const float* srcF = ws + PAF_OFF;
    unsigned* mp = (unsigned*)(ws + MP_OFF);
    int n0 = blockIdx.x * 64;
    #pragma unroll
    for (int i = 0; i < 16; i++){
        int idx = i*256 + threadIdx.x;
        int nl = idx >> 6, f = idx & 63;
        int node = n0 + nl;
        t[nl][f] = (node < N) ? srcT[(size_t)node*64 + f] : 0.f;
        u[nl][f] = (node < N) ? srcF[(size_t)node*64 + f] : 0.f;
    }
    __syncthreads();
    #pragma unroll
    for (int i = 0; i < 16; i++){
        int idx = i*256 + threadIdx.x;
        int fw = idx >> 6, nl = idx & 63;
        int node = n0 + nl;
        if (node < N)
            mp[(size_t)fw*N + node] = (unsigned)f2b(t[nl][fw]) | ((unsigned)f2b(u[nl][fw]) << 16);
    }
}

// ---- gate z+r: j-tile 8, grid 196x8, packed mt|mf stream ----
__global__ __launch_bounds__(256) void gate_zr(float* __restrict__ ws){
    int node = blockIdx.x * 256 + threadIdx.x;
    if (node >= N) return;
    int tl = blockIdx.y, j0 = tl * 8;
    const float* W = ws + NWZR_OFF + j0;
    const unsigned short* hb = (const unsigned short*)(ws + HB_OFF);
    const unsigned* mp = (const unsigned*)(ws + MP_OFF);
    float p0 = ws[PRB0_OFF+node], p1 = ws[PRB1_OFF+node];
    float cT = ws[CNT_OFF+node], cF = ws[CNT_OFF+N+node];
    float az[8], ar[8];
    #pragma unroll
    for (int j = 0; j < 8; j++){
        az[j] = ws[GB_OFF + j0 + j]
              + p0*W[192*128+j] + p1*W[193*128+j] + cT*W[194*128+j] + cF*W[195*128+j];
        ar[j] = ws[GB_OFF + 64 + j0 + j]
              + p0*W[192*128+64+j] + p1*W[193*128+64+j] + cT*W[194*128+64+j] + cF*W[195*128+64+j];
    }
    #pragma unroll 4
    for (int k = 0; k < 64; k++){
        float aH = b2f(hb[(size_t)k*N + node]);
        unsigned m = mp[(size_t)k*N + node];
        float aT = blo(m), aF = bhi(m);
        const float* wH = W + (size_t)k*128;
        const float* wT = W + (size_t)(64+k)*128;
        const float* wF = W + (size_t)(128+k)*128;
        #pragma unroll
        for (int j = 0; j < 8; j++){
            az[j] = fmaf(aH, wH[j], fmaf(aT, wT[j], fmaf(aF, wF[j], az[j])));
            ar[j] = fmaf(aH, wH[64+j], fmaf(aT, wT[64+j], fmaf(aF, wF[64+j], ar[j])));
        }
    }
    unsigned short* RH = (unsigned short*)(ws + RH_OFF);
    #pragma unroll
    for (int j = 0; j < 8; j++){
        size_t off = (size_t)(j0+j)*N + node;
        ws[AL_OFF + off] = sigm(az[j]);
        RH[off] = f2b(sigm(ar[j]) * b2f(hb[off]));
    }
}

// ---- gate corr + update: j-tile 8, grid 196x8 ----
__global__ __launch_bounds__(256) void gate_corr(const int* __restrict__ tags,
                                                 float* __restrict__ ws){
    int node = blockIdx.x * 256 + threadIdx.x;
    if (node >= N) return;
    int tl = blockIdx.y, j0 = tl*8;
    const float* W = ws + NCW_OFF + j0;
    const unsigned short* RH = (const unsigned short*)(ws + RH_OFF);
    const unsigned* mp = (const unsigned*)(ws + MP_OFF);
    float p0 = ws[PRB0_OFF+node], p1 = ws[PRB1_OFF+node];
    float cT = ws[CNT_OFF+node], cF = ws[CNT_OFF+N+node];
    float acc[8];
    #pragma unroll
    for (int j = 0; j < 8; j++)
        acc[j] = ws[CB_OFF + j0 + j]
               + p0*W[192*64+j] + p1*W[193*64+j] + cT*W[194*64+j] + cF*W[195*64+j];
    #pragma unroll 4
    for (int k = 0; k < 64; k++){
        float aR = b2f(RH[(size_t)k*N + node]);
        unsigned m = mp[(size_t)k*N + node];
        float aT = blo(m), aF = bhi(m);
        const float* wR = W + (size_t)k*64;
        const float* wT = W + (size_t)(64+k)*64;
        const float* wF = W + (size_t)(128+k)*64;
        #pragma unroll
        for (int j = 0; j < 8; j++)
            acc[j] = fmaf(aR, wR[j], fmaf(aT, wT[j], fmaf(aF, wF[j], acc[j])));
    }
    int tg = tags[node];
    unsigned short* hb = (unsigned short*)(ws + HB_OFF);
    #pragma unroll
    for (int j = 0; j < 8; j++){
        size_t off = (size_t)(j0+j)*N + node;
        float hn = fmaf(ws[AL_OFF+off], tanhf(acc[j]), ws[HF_OFF+off]);
        if (tg == 1) hn = ws[H0F_OFF+off];
        ws[HF_OFF+off] = hn;
        hb[off] = f2b(hn);
    }
}

// ---- decode stage 1: j-tile 16, grid 196x4, bf16 src -> f32 dst ----
__global__ __launch_bounds__(256) void dec1hf(const unsigned short* __restrict__ src,
                                              float* __restrict__ dst,
                                              float* __restrict__ ws){
    int node = blockIdx.x * 256 + threadIdx.x;
    if (node >= N) return;
    int j0 = blockIdx.y * 16;
    float acc[16];
    #pragma unroll
    for (int j = 0; j < 16; j++) acc[j] = ws[DB1_OFF + j0 + j];
    #pragma unroll 4
    for (int k = 0; k < 64; k++){
        float a = b2f(src[(size_t)k*N + node]);
        const float* wr = ws + DW1_OFF + (size_t)k*64 + j0;
        #pragma unroll
        for (int j = 0; j < 16; j++) acc[j] = fmaf(a, wr[j], acc[j]);
    }
    #pragma unroll
    for (int j = 0; j < 16; j++)
        dst[(size_t)(j0+j)*N + node] = fmaxf(acc[j], 0.f);
}

// ---- decode stage 1: j-tile 16, grid 196x4, bf16 src -> bf16 dst ----
__global__ __launch_bounds__(256) void dec1hb(const unsigned short* __restrict__ src,
                                              unsigned short* __restrict__ dst,
                                              float* __restrict__ ws){
    int node = blockIdx.x * 256 + threadIdx.x;
    if (node >= N) return;
    int j0 = blockIdx.y * 16;
    float acc[16];
    #pragma unroll
    for (int j = 0; j < 16; j++) acc[j] = ws[DB1_OFF + j0 + j];
    #pragma unroll 4
    for (int k = 0; k < 64; k++){
        float a = b2f(src[(size_t)k*N + node]);
        const float* wr = ws + DW1_OFF + (size_t)k*64 + j0;
        #pragma unroll
        for (int j = 0; j < 16; j++) acc[j] = fmaf(a, wr[j], acc[j]);
    }
    #pragma unroll
    for (int j = 0; j < 16; j++)
        dst[(size_t)(j0+j)*N + node] = f2b(fmaxf(acc[j], 0.f));
}

// ---- calc_u: u = T1 . DW2 with 4 independent partial sums (ILP) ----
__global__ __launch_bounds__(256) void calc_u(float* __restrict__ ws){
    int node = blockIdx.x * 256 + threadIdx.x;
    if (node >= N) return;
    const float* T1 = ws + T1_OFF;
    float u0 = 0.f, u1 = 0.f, u2 = 0.f, u3 = 0.f;
    #pragma unroll 4
    for (int j = 0; j < 16; j++){
        u0 = fmaf(T1[(size_t)(4*j  )*N + node], ws[DW2_OFF + 4*j  ], u0);
        u1 = fmaf(T1[(size_t)(4*j+1)*N + node], ws[DW2_OFF + 4*j+1], u1);
        u2 = fmaf(T1[(size_t)(4*j+2)*N + node], ws[DW2_OFF + 4*j+2], u2);
        u3 = fmaf(T1[(size_t)(4*j+3)*N + node], ws[DW2_OFF + 4*j+3], u3);
    }
    ws[UV_OFF+node] = (u0 + u1) + (u2 + u3) + ws[DB2_OFF];
}

// ---- decode stage 2 + encode(u) + enc loss: reads precomputed UV ----
__global__ __launch_bounds__(256) void enc_u(int step, float* __restrict__ ws){
    int node = blockIdx.x * 256 + threadIdx.x;
    float encA = 0.f;
    if (node < N){
        int j0 = blockIdx.y * 16;
        float u = ws[UV_OFF+node];
        float acc[16];
        #pragma unroll
        for (int j = 0; j < 16; j++) acc[j] = ws[EB2_OFF + j0 + j];
        for (int k = 0; k < 64; k++){
            float t = fmaxf(fmaf(u, ws[EW1_OFF+k], ws[EB1_OFF+k]), 0.f);
            const float* wr = ws + EW2_OFF + (size_t)k*64 + j0;
            #pragma unroll
            for (int j = 0; j < 16; j++) acc[j] = fmaf(t, wr[j], acc[j]);
        }
        unsigned short* ev = (unsigned short*)(ws + EV_OFF);
        #pragma unroll
        for (int j = 0; j < 16; j++){
            size_t off = (size_t)(j0+j)*N + node;
            ev[off] = f2b(acc[j]);
            float d = acc[j] - ws[HF_OFF+off];
            encA += d*d;
        }
    }
    encA = wave_sum(encA);
    if ((threadIdx.x & 63) == 0) atomicAdd(&ws[LOSS_OFF + step*3 + 1], encA);
}

// ---- final: u2 = dec(E) (bf16 T1, 4-way ILP), auto loss, residual, res loss ----
__global__ __launch_bounds__(256) void aux_res(int step, const void* __restrict__ y,
                                               float* __restrict__ ws){
    const int* wsI = (const int*)ws;
    int node = blockIdx.x * 256 + threadIdx.x;
    bool isbf = ws[FLAG_OFF] > 0.5f;
    float autoA = 0.f, resA = 0.f;
    if (node < N){
        const unsigned short* T1u = (const unsigned short*)(ws + T1_OFF);
        float u0 = 0.f, u1 = 0.f, u2s = 0.f, u3 = 0.f;
        #pragma unroll 4
        for (int j = 0; j < 16; j++){
            u0  = fmaf(b2f(T1u[(size_t)(4*j  )*N + node]), ws[DW2_OFF + 4*j  ], u0);
            u1  = fmaf(b2f(T1u[(size_t)(4*j+1)*N + node]), ws[DW2_OFF + 4*j+1], u1);
            u2s = fmaf(b2f(T1u[(size_t)(4*j+2)*N + node]), ws[DW2_OFF + 4*j+2], u2s);
            u3  = fmaf(b2f(T1u[(size_t)(4*j+3)*N + node]), ws[DW2_OFF + 4*j+3], u3);
        }
        float u2 = (u0 + u1) + (u2s + u3) + ws[DB2_OFF];
        float u = ws[UV_OFF+node];
        float ad = u2 - u;
        autoA = ad*ad;
        float acc = 0.f;
        int beg = wsI[FRP_OFF+node], end = wsI[FRP_OFF+node+1];
        const uint4* rrec = (const uint4*)(ws + RREC_OFF);
        for (int p = beg; p < end; p++){
            uint4 q = rrec[p];
            acc = fmaf(bhi(q.z), ws[UV_OFF + (int)(q.x & 0xffffu)], acc);
        }
        float d = acc - ldv(y, node, isbf);
        resA = d*d;
    }
    autoA = wave_sum(autoA);
    resA = wave_sum(resA);
    if ((threadIdx.x & 63) == 0){
        atomicAdd(&ws[LOSS_OFF + step*3 + 2], autoA);
        atomicAdd(&ws[LOSS_OFF + step*3], resA);
    }
}

// ---- output writer ----
__global__ __launch_bounds__(256) void write_out(void* __restrict__ outp,
                                                 const float* __restrict__ ws){
    int i = blockIdx.x * 256 + threadIdx.x;
    if (i > N) return;
    bool isbf = ws[FLAG_OFF] > 0.5f;
    float v;
    if (i < N){
        v = ws[UV_OFF+i];
    } else {
        const float* L = ws + LOSS_OFF;
        float inv = 1.f / (float)N, invl = 1.f / ((float)N * 64.f);
        v = 0.9f*L[0]*inv + L[1]*invl + L[2]*inv
          +      L[3]*inv + L[4]*invl + L[5]*inv;
    }
    if (isbf) ((unsigned short*)outp)[i] = f2b(v);
    else      ((float*)outp)[i] = v;
}

extern "C" void kernel_launch(void* const* d_in, const int* in_sizes, int n_in,
                              void* d_out, int out_size, void* d_ws, size_t ws_size,
                              hipStream_t stream){
    const void* x    = d_in[0];
    const void* y    = d_in[2];
    const int* tags  = (const int*)d_in[3];
    const int* ei    = (const int*)d_in[4];
    const void* attr = d_in[5];
    const void* aij  = d_in[6];
    const void* prb  = d_in[7];
    WPtrs P;
    P.ptW1 = d_in[8];  P.ptb1 = d_in[9];  P.ptW2 = d_in[10]; P.ptb2 = d_in[11];
    P.pfW1 = d_in[12]; P.pfb1 = d_in[13]; P.pfW2 = d_in[14]; P.pfb2 = d_in[15];
    P.zkW  = d_in[16]; P.zkb  = d_in[17]; P.rkW  = d_in[18]; P.rkb  = d_in[19];
    P.cW   = d_in[20]; P.cb   = d_in[21];
    P.eW1  = d_in[22]; P.eb1  = d_in[23]; P.eW2  = d_in[24]; P.eb2  = d_in[25];
    P.dW1  = d_in[26]; P.db1  = d_in[27]; P.dW2  = d_in[28]; P.db2  = d_in[29];
    float* ws = (float*)d_ws;
    int* wsI = (int*)d_ws;

    detect_kernel<<<1, 256, 0, stream>>>(y, ws);
    prep_kernel<<<(PREP_TOTAL + 255)/256, 256, 0, stream>>>(P, ws);
    prep2_kernel<<<(PREP2_TOTAL + 255)/256, 256, 0, stream>>>(ws);
    setup_node<<<196, 256, 0, stream>>>(prb, ws);
    bucket_hist<<<196, 256, 0, stream>>>(ei, wsI);
    bucket_scan<<<dim3(1, 2), 256, 0, stream>>>(wsI);
    scatter_binA<<<196, 256, 0, stream>>>(ei, attr, aij, ws);
    deg_count<<<dim3(196, 2), 256, 0, stream>>>(ws);
    scan1<<<dim3(196, 2), 256, 0, stream>>>(wsI);
    scan2<<<dim3(1, 2), 256, 0, stream>>>(wsI);
    scan3<<<dim3(196, 2), 256, 0, stream>>>(wsI);
    scatter_binB<<<dim3(196, 2), 256, 0, stream>>>(ws);
    encode_init<<<dim3(196, 2), 256, 0, stream>>>(x, ws);
    unsigned short* hb = (unsigned short*)(ws + HB_OFF);
    unsigned short* ev = (unsigned short*)(ws + EV_OFF);
    for (int step = 0; step < 2; step++){
        node_pre<<<dim3(196, 8), 256, 0, stream>>>(ws);
        gather_msgs<0><<<2048, 256, 0, stream>>>(ws);
        gather_msgs<1><<<2048, 256, 0, stream>>>(ws);
        transpose_msg<<<782, 256, 0, stream>>>(ws);
        gate_zr<<<dim3(196, 8), 256, 0, stream>>>(ws);
        gate_corr<<<dim3(196, 8), 256, 0, stream>>>(tags, ws);
        dec1hf<<<dim3(196, 4), 256, 0, stream>>>(hb, ws + T1_OFF, ws);
        calc_u<<<196, 256, 0, stream>>>(ws);
        enc_u<<<dim3(196, 4), 256, 0, stream>>>(step, ws);
        dec1hb<<<dim3(196, 4), 256, 0, stream>>>(ev, (unsigned short*)(ws + T1_OFF), ws);
        aux_res<<<196, 256, 0, stream>>>(step, y, ws);
    }
    write_out<<<197, 256, 0, stream>>>(d_out, ws);
}